// Round 12
// baseline (204.947 us; speedup 1.0000x reference)
//
#include <hip/hip_runtime.h>
#include <math.h>

constexpr int D  = 1024;
constexpr int H  = 16;
constexpr int HD = 64;
constexpr int B  = 2;
constexpr int T  = 2048;
constexpr int M  = B * T;   // 4096

constexpr size_t XSZ = (size_t)M * D;   // 4,194,304
constexpr size_t WSZ = (size_t)D * D;   // 1,048,576

typedef float  f32x4   __attribute__((ext_vector_type(4)));
typedef float  f32x16  __attribute__((ext_vector_type(16)));
typedef __bf16 bf16x8  __attribute__((ext_vector_type(8)));
typedef __bf16 bf16x4  __attribute__((ext_vector_type(4)));
typedef unsigned u32x2 __attribute__((ext_vector_type(2)));
typedef unsigned u32x4 __attribute__((ext_vector_type(4)));

static __device__ inline f32x4 mfma16(bf16x8 a, bf16x8 b, f32x4 c) {
  return __builtin_amdgcn_mfma_f32_16x16x32_bf16(a, b, c, 0, 0, 0);
}
static __device__ inline f32x16 mfma32(bf16x8 a, bf16x8 b, f32x16 c) {
  return __builtin_amdgcn_mfma_f32_32x32x16_bf16(a, b, c, 0, 0, 0);
}
// pack two f32 -> u32 of 2 bf16 (lo = a, hi = b); no builtin on gfx950
static __device__ inline unsigned cvtpk(float a, float b) {
  unsigned r;
  asm("v_cvt_pk_bf16_f32 %0, %1, %2" : "=v"(r) : "v"(a), "v"(b));
  return r;
}
static __device__ inline u32x2 plswap(unsigned a, unsigned b) {
  return __builtin_amdgcn_permlane32_swap(a, b, false, false);
}
// async global->LDS, 16B per lane (dest = wave-uniform base + lane*16)
static __device__ inline void gload16(const __bf16* g, __bf16* l) {
  __builtin_amdgcn_global_load_lds(
      (const __attribute__((address_space(1))) void*)g,
      (__attribute__((address_space(3))) void*)l, 16, 0, 0);
}

// ---------------------------------------------------------------------------
// Fused fp32->bf16 convert of x + 4 weights into contiguous bf16 workspace.
// ---------------------------------------------------------------------------
__global__ __launch_bounds__(256)
void cvt_all(const float* __restrict__ x, const float* __restrict__ wq,
             const float* __restrict__ wk, const float* __restrict__ wv,
             const float* __restrict__ wo, __bf16* __restrict__ out) {
  size_t idx = ((size_t)blockIdx.x * 256 + threadIdx.x) * 8;
  const float* src;
  if      (idx < XSZ)            src = x  + idx;
  else if (idx < XSZ + WSZ)      src = wq + (idx - XSZ);
  else if (idx < XSZ + 2 * WSZ)  src = wk + (idx - XSZ - WSZ);
  else if (idx < XSZ + 3 * WSZ)  src = wv + (idx - XSZ - 2 * WSZ);
  else                           src = wo + (idx - XSZ - 3 * WSZ);
  float4 a = *reinterpret_cast<const float4*>(src);
  float4 b = *reinterpret_cast<const float4*>(src + 4);
  bf16x8 o;
  o[0] = (__bf16)a.x; o[1] = (__bf16)a.y; o[2] = (__bf16)a.z; o[3] = (__bf16)a.w;
  o[4] = (__bf16)b.x; o[5] = (__bf16)b.y; o[6] = (__bf16)b.z; o[7] = (__bf16)b.w;
  *reinterpret_cast<bf16x8*>(out + idx) = o;
}

// ---------------------------------------------------------------------------
// MFMA GEMM, global_load_lds staging. C[m,n] = sum_k A[m,k]*W[n,k].
// MODE 1: fused QKV; Q gets softmax-scale (0.125*log2e) folded into RoPE.
// MODE 0: single GEMM (wo), fp32 out.
// ---------------------------------------------------------------------------
template<int MODE>
__global__ __launch_bounds__(512)
void gemm_mfma(const __bf16* __restrict__ A,
               const __bf16* __restrict__ W0, const __bf16* __restrict__ W1,
               const __bf16* __restrict__ W2,
               const float* __restrict__ cosT, const float* __restrict__ sinT,
               void* __restrict__ out0, void* __restrict__ out1,
               void* __restrict__ out2) {
  __shared__ __bf16 As[128 * 64];
  __shared__ __bf16 Bs[128 * 64];

  const int tid  = threadIdx.x;
  const int lane = tid & 63;
  const int w    = tid >> 6;     // 0..7
  const int wm   = w >> 1;       // 0..3 (32 rows each)
  const int wn   = w & 1;        // 0..1 (64 cols each)
  const int l15  = lane & 15, lg = lane >> 4;
  const int m0   = blockIdx.y * 128;

  int which, n0;
  const __bf16* Bw;
  if (MODE == 1) {
    which = blockIdx.x >> 3;
    n0 = (blockIdx.x & 7) * 128;
    Bw = which == 0 ? W0 : which == 1 ? W1 : W2;
  } else {
    which = 0;
    n0 = blockIdx.x * 128;
    Bw = W0;
  }

  f32x4 acc[2][4];
  #pragma unroll
  for (int i = 0; i < 2; ++i)
    #pragma unroll
    for (int j = 0; j < 4; ++j) acc[i][j] = (f32x4){0.f, 0.f, 0.f, 0.f};

  const int e0 = tid * 8;        // 0..4095
  const int r0 = e0 >> 6;        // 0..63
  const int c0 = e0 & 63;

  for (int k0 = 0; k0 < 1024; k0 += 64) {
    const __bf16* ga = A  + (size_t)(m0 + r0) * 1024 + k0 + c0;
    const __bf16* gb = Bw + (size_t)(n0 + r0) * 1024 + k0 + c0;
    gload16(ga,             As + e0);
    gload16(ga + 64 * 1024, As + e0 + 4096);
    gload16(gb,             Bs + e0);
    gload16(gb + 64 * 1024, Bs + e0 + 4096);
    __syncthreads();

    #pragma unroll
    for (int ks = 0; ks < 2; ++ks) {
      bf16x8 af[2], bfr[4];
      #pragma unroll
      for (int mt = 0; mt < 2; ++mt)
        af[mt] = *reinterpret_cast<const bf16x8*>(
            &As[(wm * 32 + mt * 16 + l15) * 64 + ks * 32 + lg * 8]);
      #pragma unroll
      for (int nt = 0; nt < 4; ++nt)
        bfr[nt] = *reinterpret_cast<const bf16x8*>(
            &Bs[(wn * 64 + nt * 16 + l15) * 64 + ks * 32 + lg * 8]);
      #pragma unroll
      for (int mt = 0; mt < 2; ++mt)
        #pragma unroll
        for (int nt = 0; nt < 4; ++nt)
          acc[mt][nt] = mfma16(af[mt], bfr[nt], acc[mt][nt]);
    }
    __syncthreads();
  }

  if (MODE == 0) {
    float* o = (float*)out0;
    #pragma unroll
    for (int mt = 0; mt < 2; ++mt) {
      const int mb = m0 + wm * 32 + mt * 16 + lg * 4;
      #pragma unroll
      for (int nt = 0; nt < 4; ++nt) {
        const int n = n0 + wn * 64 + nt * 16 + l15;
        #pragma unroll
        for (int r = 0; r < 4; ++r)
          o[(size_t)(mb + r) * 1024 + n] = acc[mt][nt][r];
      }
    }
  } else if (which < 2) {
    // Q or K: RoPE fused; Q additionally scaled by 0.125*log2(e).
    __bf16* dst = which == 0 ? (__bf16*)out0 : (__bf16*)out1;
    const float qs = (which == 0) ? 0.180336880f : 1.0f;
    const int h = (n0 + wn * 64) >> 6;
    #pragma unroll
    for (int mt = 0; mt < 2; ++mt) {
      const int tb   = m0 + wm * 32 + mt * 16 + lg * 4;
      const int bb   = tb >> 11;
      const int tloc = tb & 2047;
      #pragma unroll
      for (int r = 0; r < 4; ++r) {
        const int t = tloc + r;
        #pragma unroll
        for (int nt = 0; nt < 2; ++nt) {
          const int hd = nt * 16 + l15;
          const float c = cosT[t * HD + hd];
          const float s = sinT[t * HD + hd];
          const float v1 = acc[mt][nt][r];
          const float v2 = acc[mt][nt + 2][r];
          const size_t base = (((size_t)(bb * H + h)) * T + t) * HD;
          dst[base + hd]      = (__bf16)((v1 * c - v2 * s) * qs);
          dst[base + hd + 32] = (__bf16)((v2 * c + v1 * s) * qs);
        }
      }
    }
  } else {
    // V: transposed store [bh][hd][t]
    __bf16* dst = (__bf16*)out2;
    const int h = (n0 + wn * 64) >> 6;
    #pragma unroll
    for (int mt = 0; mt < 2; ++mt) {
      const int tb = m0 + wm * 32 + mt * 16 + lg * 4;
      const int bb = tb >> 11;
      const int t0 = tb & 2047;
      #pragma unroll
      for (int nt = 0; nt < 4; ++nt) {
        const int hd = nt * 16 + l15;
        bf16x4 ov;
        #pragma unroll
        for (int r = 0; r < 4; ++r) ov[r] = (__bf16)acc[mt][nt][r];
        *reinterpret_cast<bf16x4*>(
            &dst[(((size_t)(bb * H + h)) * HD + hd) * T + t0]) = ov;
      }
    }
  }
}

// ---------------------------------------------------------------------------
// attn_v10: v9 + split-K over key-tile parity (2 waves per (bh,qt) job).
// Evidence (v8 vs v9): identical time with 79MB vs 12MB HBM traffic -> not
// memory-bound; Occupancy 14% ~= 1.1 waves/SIMD effective -> serial-chain-
// bound with no overlap. Fix: 4 waves/SIMD with flat balance.
//   - Block = 4 waves = 2 jobs {v, 63-v} (65 tiles/block constant).
//   - Job split by tile parity: wave wp in {0,1} does tiles wp, wp+2, ...
//     (both waves sweep the key range together -> L2 co-locality).
//   - Grid 1024 -> 4 blocks/CU co-resident; job-slot XOR'd with dispatch
//     round so each SIMD gets ~65 tiles across 4 concurrent waves.
//   - id%8 = bh&7 keeps the v9 XCD locality (4 bh -> 2MB K/V per L2).
//   - Per-job merge of (m,l,oacc) partials via padded LDS (stride 34 f32,
//     2-way = free), one __syncthreads total.
// Q: [bh][t][64] pre-scaled by 0.125*log2e. K: [bh][t][64]. Vt: [bh][64][t].
// ---------------------------------------------------------------------------
__global__ __launch_bounds__(256, 4)
void attn_v10(const __bf16* __restrict__ Q, const __bf16* __restrict__ K,
              const __bf16* __restrict__ Vt, __bf16* __restrict__ Ob) {
  __shared__ float Mrg[2][64][34];   // [job][lane][oacc0 16 | oacc1 16 | m | l]

  const int tid  = threadIdx.x;
  const int lane = tid & 63;
  const int w    = tid >> 6;          // 0..3
  const int l31  = lane & 31;
  const int hi   = lane >> 5;         // 0..1

  const int id = blockIdx.x;          // 0..1023
  const int r  = id >> 8;             // dispatch round 0..3
  const int c  = id & 255;
  const int bh = (c & 7) + 8 * r;     // XCD = id%8 = bh&7
  const int v  = c >> 3;              // 0..31

  const int J  = (w >> 1) ^ (r & 1);  // job slot (round-swapped for balance)
  const int wp = w & 1;               // key-tile parity of this wave
  const int qt = (J == 0) ? v : 63 - v;
  const int q0w = qt * 32;

  const __bf16* Qg = Q  + (size_t)bh * T * HD;
  const __bf16* Kg = K  + (size_t)bh * T * HD;
  const __bf16* Vg = Vt + (size_t)bh * HD * T;

  // Q B-fragments: col=q=l31; per k-step st: elements st*16 + hi*8 ..+8
  bf16x8 qfr[4];
  #pragma unroll
  for (int st = 0; st < 4; ++st)
    qfr[st] = *reinterpret_cast<const bf16x8*>(
        Qg + (size_t)(q0w + l31) * HD + st * 16 + hi * 8);

  float m_run = -INFINITY, l_run = 0.f;
  f32x16 oacc0, oacc1;
  #pragma unroll
  for (int i = 0; i < 16; ++i) { oacc0[i] = 0.f; oacc1[i] = 0.f; }

  // K frag (A): row=key=l31, k elems hi*8; V frag (A): row=hd, k elems hi*8
  const __bf16* kbase = Kg + (size_t)l31 * HD + hi * 8;
  const __bf16* vbase = Vg + (size_t)l31 * T + hi * 8;

#define LOADKV(K0, K1, K2, K3, V00, V01, V10, V11, jj)                        \
  do {                                                                        \
    const __bf16* _kp = kbase + (size_t)(jj) * 32 * HD;                       \
    K0 = *reinterpret_cast<const bf16x8*>(_kp);                               \
    K1 = *reinterpret_cast<const bf16x8*>(_kp + 16);                          \
    K2 = *reinterpret_cast<const bf16x8*>(_kp + 32);                          \
    K3 = *reinterpret_cast<const bf16x8*>(_kp + 48);                          \
    const __bf16* _vp = vbase + (size_t)(jj) * 32;                            \
    V00 = *reinterpret_cast<const bf16x8*>(_vp);                              \
    V01 = *reinterpret_cast<const bf16x8*>(_vp + 16);                         \
    V10 = *reinterpret_cast<const bf16x8*>(_vp + (size_t)32 * T);             \
    V11 = *reinterpret_cast<const bf16x8*>(_vp + (size_t)32 * T + 16);        \
  } while (0)

#define TILE(K0, K1, K2, K3, V00, V01, V10, V11, jj)                          \
  do {                                                                        \
    f32x16 sva, svb;                                                          \
    _Pragma("unroll")                                                         \
    for (int _i = 0; _i < 16; ++_i) { sva[_i] = 0.f; svb[_i] = 0.f; }         \
    sva = mfma32(K0, qfr[0], sva);                                            \
    svb = mfma32(K1, qfr[1], svb);                                            \
    sva = mfma32(K2, qfr[2], sva);                                            \
    svb = mfma32(K3, qfr[3], svb);                                            \
    f32x16 sv;                                                                \
    _Pragma("unroll")                                                         \
    for (int _i = 0; _i < 16; ++_i) sv[_i] = sva[_i] + svb[_i];               \
    if ((jj) == qt) { /* diagonal tile: causal mask */                        \
      const int _q = q0w + l31;                                               \
      const int _kb = (jj) * 32 + 4 * hi;                                     \
      _Pragma("unroll")                                                       \
      for (int _r = 0; _r < 16; ++_r) {                                       \
        const int _key = _kb + (_r & 3) + 8 * (_r >> 2);                      \
        if (_key > _q) sv[_r] = -INFINITY;                                    \
      }                                                                       \
    }                                                                         \
    float _mx[8];                                                             \
    _Pragma("unroll")                                                         \
    for (int _i = 0; _i < 8; ++_i) _mx[_i] = fmaxf(sv[_i], sv[_i + 8]);       \
    _Pragma("unroll")                                                         \
    for (int _s = 4; _s > 0; _s >>= 1)                                        \
      _Pragma("unroll")                                                       \
      for (int _i = 0; _i < 4; ++_i)                                          \
        if (_i < _s) _mx[_i] = fmaxf(_mx[_i], _mx[_i + _s]);                  \
    union { float f; unsigned u; } _cv; _cv.f = _mx[0];                       \
    u32x2 _sw = plswap(_cv.u, _cv.u);                                         \
    union { unsigned u; float f; } _c0, _c1; _c0.u = _sw[0]; _c1.u = _sw[1];  \
    const float _pmax = fmaxf(_c0.f, _c1.f);                                  \
    if (__any(_pmax > m_run + 8.f)) {                                         \
      const float _mn = fmaxf(m_run, _pmax);                                  \
      const float _rs = exp2f(m_run - _mn);                                   \
      l_run *= _rs;                                                           \
      _Pragma("unroll")                                                       \
      for (int _i = 0; _i < 16; ++_i) { oacc0[_i] *= _rs; oacc1[_i] *= _rs; } \
      m_run = _mn;                                                            \
    }                                                                         \
    _Pragma("unroll")                                                         \
    for (int _i = 0; _i < 16; ++_i) sv[_i] = exp2f(sv[_i] - m_run);           \
    float _sm[8];                                                             \
    _Pragma("unroll")                                                         \
    for (int _i = 0; _i < 8; ++_i) _sm[_i] = sv[_i] + sv[_i + 8];             \
    _Pragma("unroll")                                                         \
    for (int _s = 4; _s > 0; _s >>= 1)                                        \
      _Pragma("unroll")                                                       \
      for (int _i = 0; _i < 4; ++_i)                                          \
        if (_i < _s) _sm[_i] += _sm[_i + _s];                                 \
    l_run += _sm[0];                                                          \
    unsigned _cp[8];                                                          \
    _Pragma("unroll")                                                         \
    for (int _m = 0; _m < 4; ++_m) {                                          \
      _cp[2 * _m]     = cvtpk(sv[4 * _m],     sv[4 * _m + 1]);                \
      _cp[2 * _m + 1] = cvtpk(sv[4 * _m + 2], sv[4 * _m + 3]);                \
    }                                                                         \
    {                                                                         \
      u32x2 _r0 = plswap(_cp[0], _cp[2]);                                     \
      u32x2 _r1 = plswap(_cp[1], _cp[3]);                                     \
      union { u32x4 u; bf16x8 v; } _pu;                                       \
      _pu.u = (u32x4){_r0[0], _r1[0], _r0[1], _r1[1]};                        \
      oacc0 = mfma32(V00, _pu.v, oacc0);                                      \
      oacc1 = mfma32(V10, _pu.v, oacc1);                                      \
    }                                                                         \
    {                                                                         \
      u32x2 _r0 = plswap(_cp[4], _cp[6]);                                     \
      u32x2 _r1 = plswap(_cp[5], _cp[7]);                                     \
      union { u32x4 u; bf16x8 v; } _pu;                                       \
      _pu.u = (u32x4){_r0[0], _r1[0], _r0[1], _r1[1]};                        \
      oacc0 = mfma32(V01, _pu.v, oacc0);                                      \
      oacc1 = mfma32(V11, _pu.v, oacc1);                                      \
    }                                                                         \
  } while (0)

  bf16x8 kA0, kA1, kA2, kA3, vA00, vA01, vA10, vA11;
  bf16x8 kB0, kB1, kB2, kB3, vB00, vB01, vB10, vB11;

  // This wave's tiles: wp, wp+2, ..., <= qt  (register-pipelined 1 ahead)
  int jj = wp;
  if (jj <= qt) {
    LOADKV(kA0, kA1, kA2, kA3, vA00, vA01, vA10, vA11, jj);
    #pragma unroll 1
    for (;;) {
      if (jj + 2 <= qt)
        LOADKV(kB0, kB1, kB2, kB3, vB00, vB01, vB10, vB11, jj + 2);
      TILE(kA0, kA1, kA2, kA3, vA00, vA01, vA10, vA11, jj);
      if (jj + 2 > qt) break;
      if (jj + 4 <= qt)
        LOADKV(kA0, kA1, kA2, kA3, vA00, vA01, vA10, vA11, jj + 4);
      TILE(kB0, kB1, kB2, kB3, vB00, vB01, vB10, vB11, jj + 2);
      if (jj + 4 > qt) break;
      jj += 4;
    }
  }
#undef TILE
#undef LOADKV

  // ---- split-K merge: parity-1 wave publishes partials, parity-0 merges ---
  float* row = &Mrg[J][lane][0];
  if (wp == 1) {
    #pragma unroll
    for (int i = 0; i < 16; ++i) row[i]      = oacc0[i];
    #pragma unroll
    for (int i = 0; i < 16; ++i) row[16 + i] = oacc1[i];
    row[32] = m_run;
    row[33] = l_run;
  }
  __syncthreads();
  if (wp == 0) {
    const float mB = row[32], lB = row[33];
    const float mS = fmaxf(m_run, mB);
    const float sA = exp2f(m_run - mS);
    const float sB = exp2f(mB - mS);
    float l_lane = l_run * sA + lB * sB;
    const float l_tot = l_lane + __shfl_xor(l_lane, 32);
    const float inv = 1.f / l_tot;

    const int b = bh >> 4, h = bh & 15;
    const int q_abs = q0w + l31;
    const size_t rowbase = ((size_t)(b * T + q_abs)) * 1024 + h * 64;
    #pragma unroll
    for (int rg = 0; rg < 4; ++rg) {
      bf16x4 o0, o1;
      #pragma unroll
      for (int rr = 0; rr < 4; ++rr) {
        const int i = rg * 4 + rr;
        o0[rr] = (__bf16)((oacc0[i] * sA + row[i]      * sB) * inv);
        o1[rr] = (__bf16)((oacc1[i] * sA + row[16 + i] * sB) * inv);
      }
      *reinterpret_cast<bf16x4*>(&Ob[rowbase + rg * 8 + hi * 4])      = o0;
      *reinterpret_cast<bf16x4*>(&Ob[rowbase + 32 + rg * 8 + hi * 4]) = o1;
    }
  }
}

// ---------------------------------------------------------------------------
extern "C" void kernel_launch(void* const* d_in, const int* in_sizes, int n_in,
                              void* d_out, int out_size, void* d_ws, size_t ws_size,
                              hipStream_t stream) {
  const float* x    = (const float*)d_in[0];
  const float* cosT = (const float*)d_in[1];
  const float* sinT = (const float*)d_in[2];
  // d_in[3] = mask (causal, analytic)
  const float* wq   = (const float*)d_in[4];
  const float* wk   = (const float*)d_in[5];
  const float* wv   = (const float*)d_in[6];
  const float* wo   = (const float*)d_in[7];
  float* out = (float*)d_out;

  __bf16* xb   = (__bf16*)d_ws;
  __bf16* wqb  = xb  + XSZ;
  __bf16* wkb  = wqb + WSZ;
  __bf16* wvb  = wkb + WSZ;
  __bf16* wob  = wvb + WSZ;
  __bf16* Qh   = wob + WSZ;      // [bh][t][hd]  (pre-scaled by 0.125*log2e)
  __bf16* Kh   = Qh  + XSZ;      // [bh][t][hd]
  __bf16* Vth  = Kh  + XSZ;      // [bh][hd][t]
  __bf16* attb = Vth + XSZ;      // [M][1024]

  cvt_all<<<(XSZ + 4 * WSZ) / 8 / 256, 256, 0, stream>>>(x, wq, wk, wv, wo, xb);

  gemm_mfma<1><<<dim3(24, 32), 512, 0, stream>>>(
      xb, wqb, wkb, wvb, cosT, sinT, Qh, Kh, Vth);

  attn_v10<<<dim3(1024), 256, 0, stream>>>(Qh, Kh, Vth, attb);

  gemm_mfma<0><<<dim3(8, 32), 512, 0, stream>>>(
      attb, wob, nullptr, nullptr, nullptr, nullptr, out, nullptr, nullptr);
}

// Round 13
// 164.424 us; speedup vs baseline: 1.2465x; 1.2465x over previous
//
#include <hip/hip_runtime.h>
#include <math.h>

constexpr int D  = 1024;
constexpr int H  = 16;
constexpr int HD = 64;
constexpr int B  = 2;
constexpr int T  = 2048;
constexpr int M  = B * T;   // 4096

constexpr size_t XSZ = (size_t)M * D;   // 4,194,304
constexpr size_t WSZ = (size_t)D * D;   // 1,048,576

typedef float  f32x4   __attribute__((ext_vector_type(4)));
typedef float  f32x16  __attribute__((ext_vector_type(16)));
typedef __bf16 bf16x8  __attribute__((ext_vector_type(8)));
typedef __bf16 bf16x4  __attribute__((ext_vector_type(4)));
typedef unsigned u32x2 __attribute__((ext_vector_type(2)));
typedef unsigned u32x4 __attribute__((ext_vector_type(4)));

static __device__ inline f32x4 mfma16(bf16x8 a, bf16x8 b, f32x4 c) {
  return __builtin_amdgcn_mfma_f32_16x16x32_bf16(a, b, c, 0, 0, 0);
}
static __device__ inline f32x16 mfma32(bf16x8 a, bf16x8 b, f32x16 c) {
  return __builtin_amdgcn_mfma_f32_32x32x16_bf16(a, b, c, 0, 0, 0);
}
// pack two f32 -> u32 of 2 bf16 (lo = a, hi = b); no builtin on gfx950
static __device__ inline unsigned cvtpk(float a, float b) {
  unsigned r;
  asm("v_cvt_pk_bf16_f32 %0, %1, %2" : "=v"(r) : "v"(a), "v"(b));
  return r;
}
static __device__ inline u32x2 plswap(unsigned a, unsigned b) {
  return __builtin_amdgcn_permlane32_swap(a, b, false, false);
}
// async global->LDS, 16B per lane (dest = wave-uniform base + lane*16)
static __device__ inline void gload16(const __bf16* g, __bf16* l) {
  __builtin_amdgcn_global_load_lds(
      (const __attribute__((address_space(1))) void*)g,
      (__attribute__((address_space(3))) void*)l, 16, 0, 0);
}

// ---------------------------------------------------------------------------
// Fused fp32->bf16 convert of x + 4 weights into contiguous bf16 workspace.
// ---------------------------------------------------------------------------
__global__ __launch_bounds__(256)
void cvt_all(const float* __restrict__ x, const float* __restrict__ wq,
             const float* __restrict__ wk, const float* __restrict__ wv,
             const float* __restrict__ wo, __bf16* __restrict__ out) {
  size_t idx = ((size_t)blockIdx.x * 256 + threadIdx.x) * 8;
  const float* src;
  if      (idx < XSZ)            src = x  + idx;
  else if (idx < XSZ + WSZ)      src = wq + (idx - XSZ);
  else if (idx < XSZ + 2 * WSZ)  src = wk + (idx - XSZ - WSZ);
  else if (idx < XSZ + 3 * WSZ)  src = wv + (idx - XSZ - 2 * WSZ);
  else                           src = wo + (idx - XSZ - 3 * WSZ);
  float4 a = *reinterpret_cast<const float4*>(src);
  float4 b = *reinterpret_cast<const float4*>(src + 4);
  bf16x8 o;
  o[0] = (__bf16)a.x; o[1] = (__bf16)a.y; o[2] = (__bf16)a.z; o[3] = (__bf16)a.w;
  o[4] = (__bf16)b.x; o[5] = (__bf16)b.y; o[6] = (__bf16)b.z; o[7] = (__bf16)b.w;
  *reinterpret_cast<bf16x8*>(out + idx) = o;
}

// ---------------------------------------------------------------------------
// MFMA GEMM, global_load_lds staging. C[m,n] = sum_k A[m,k]*W[n,k].
// MODE 1: fused QKV; Q gets softmax-scale (0.125*log2e) folded into RoPE.
// MODE 0: single GEMM (wo), fp32 out.
// ---------------------------------------------------------------------------
template<int MODE>
__global__ __launch_bounds__(512)
void gemm_mfma(const __bf16* __restrict__ A,
               const __bf16* __restrict__ W0, const __bf16* __restrict__ W1,
               const __bf16* __restrict__ W2,
               const float* __restrict__ cosT, const float* __restrict__ sinT,
               void* __restrict__ out0, void* __restrict__ out1,
               void* __restrict__ out2) {
  __shared__ __bf16 As[128 * 64];
  __shared__ __bf16 Bs[128 * 64];

  const int tid  = threadIdx.x;
  const int lane = tid & 63;
  const int w    = tid >> 6;     // 0..7
  const int wm   = w >> 1;       // 0..3 (32 rows each)
  const int wn   = w & 1;        // 0..1 (64 cols each)
  const int l15  = lane & 15, lg = lane >> 4;
  const int m0   = blockIdx.y * 128;

  int which, n0;
  const __bf16* Bw;
  if (MODE == 1) {
    which = blockIdx.x >> 3;
    n0 = (blockIdx.x & 7) * 128;
    Bw = which == 0 ? W0 : which == 1 ? W1 : W2;
  } else {
    which = 0;
    n0 = blockIdx.x * 128;
    Bw = W0;
  }

  f32x4 acc[2][4];
  #pragma unroll
  for (int i = 0; i < 2; ++i)
    #pragma unroll
    for (int j = 0; j < 4; ++j) acc[i][j] = (f32x4){0.f, 0.f, 0.f, 0.f};

  const int e0 = tid * 8;        // 0..4095
  const int r0 = e0 >> 6;        // 0..63
  const int c0 = e0 & 63;

  for (int k0 = 0; k0 < 1024; k0 += 64) {
    const __bf16* ga = A  + (size_t)(m0 + r0) * 1024 + k0 + c0;
    const __bf16* gb = Bw + (size_t)(n0 + r0) * 1024 + k0 + c0;
    gload16(ga,             As + e0);
    gload16(ga + 64 * 1024, As + e0 + 4096);
    gload16(gb,             Bs + e0);
    gload16(gb + 64 * 1024, Bs + e0 + 4096);
    __syncthreads();

    #pragma unroll
    for (int ks = 0; ks < 2; ++ks) {
      bf16x8 af[2], bfr[4];
      #pragma unroll
      for (int mt = 0; mt < 2; ++mt)
        af[mt] = *reinterpret_cast<const bf16x8*>(
            &As[(wm * 32 + mt * 16 + l15) * 64 + ks * 32 + lg * 8]);
      #pragma unroll
      for (int nt = 0; nt < 4; ++nt)
        bfr[nt] = *reinterpret_cast<const bf16x8*>(
            &Bs[(wn * 64 + nt * 16 + l15) * 64 + ks * 32 + lg * 8]);
      #pragma unroll
      for (int mt = 0; mt < 2; ++mt)
        #pragma unroll
        for (int nt = 0; nt < 4; ++nt)
          acc[mt][nt] = mfma16(af[mt], bfr[nt], acc[mt][nt]);
    }
    __syncthreads();
  }

  if (MODE == 0) {
    float* o = (float*)out0;
    #pragma unroll
    for (int mt = 0; mt < 2; ++mt) {
      const int mb = m0 + wm * 32 + mt * 16 + lg * 4;
      #pragma unroll
      for (int nt = 0; nt < 4; ++nt) {
        const int n = n0 + wn * 64 + nt * 16 + l15;
        #pragma unroll
        for (int r = 0; r < 4; ++r)
          o[(size_t)(mb + r) * 1024 + n] = acc[mt][nt][r];
      }
    }
  } else if (which < 2) {
    // Q or K: RoPE fused; Q additionally scaled by 0.125*log2(e).
    __bf16* dst = which == 0 ? (__bf16*)out0 : (__bf16*)out1;
    const float qs = (which == 0) ? 0.180336880f : 1.0f;
    const int h = (n0 + wn * 64) >> 6;
    #pragma unroll
    for (int mt = 0; mt < 2; ++mt) {
      const int tb   = m0 + wm * 32 + mt * 16 + lg * 4;
      const int bb   = tb >> 11;
      const int tloc = tb & 2047;
      #pragma unroll
      for (int r = 0; r < 4; ++r) {
        const int t = tloc + r;
        #pragma unroll
        for (int nt = 0; nt < 2; ++nt) {
          const int hd = nt * 16 + l15;
          const float c = cosT[t * HD + hd];
          const float s = sinT[t * HD + hd];
          const float v1 = acc[mt][nt][r];
          const float v2 = acc[mt][nt + 2][r];
          const size_t base = (((size_t)(bb * H + h)) * T + t) * HD;
          dst[base + hd]      = (__bf16)((v1 * c - v2 * s) * qs);
          dst[base + hd + 32] = (__bf16)((v2 * c + v1 * s) * qs);
        }
      }
    }
  } else {
    // V: transposed store [bh][hd][t]
    __bf16* dst = (__bf16*)out2;
    const int h = (n0 + wn * 64) >> 6;
    #pragma unroll
    for (int mt = 0; mt < 2; ++mt) {
      const int tb = m0 + wm * 32 + mt * 16 + lg * 4;
      const int bb = tb >> 11;
      const int t0 = tb & 2047;
      #pragma unroll
      for (int nt = 0; nt < 4; ++nt) {
        const int hd = nt * 16 + l15;
        bf16x4 ov;
        #pragma unroll
        for (int r = 0; r < 4; ++r) ov[r] = (__bf16)acc[mt][nt][r];
        *reinterpret_cast<bf16x4*>(
            &dst[(((size_t)(bb * H + h)) * HD + hd) * T + t0]) = ov;
      }
    }
  }
}

// ---------------------------------------------------------------------------
// attn_v11: v10 split-K, but __launch_bounds__(256,3) instead of (256,4).
// v10's regression was pure register spill: forcing min 4 waves/EU let the
// allocator target 64 VGPRs; the K/V register pipeline (~110 live) spilled
// to scratch -> WRITE_SIZE 292MB. Cap at 3 waves/EU (VGPR budget ~168)
// keeps the pipeline in registers AND triples v9's resident parallelism.
// Everything else identical to v10.
// ---------------------------------------------------------------------------
__global__ __launch_bounds__(256, 3)
void attn_v11(const __bf16* __restrict__ Q, const __bf16* __restrict__ K,
              const __bf16* __restrict__ Vt, __bf16* __restrict__ Ob) {
  __shared__ float Mrg[2][64][34];   // [job][lane][oacc0 16 | oacc1 16 | m | l]

  const int tid  = threadIdx.x;
  const int lane = tid & 63;
  const int w    = tid >> 6;          // 0..3
  const int l31  = lane & 31;
  const int hi   = lane >> 5;         // 0..1

  const int id = blockIdx.x;          // 0..1023
  const int r  = id >> 8;             // dispatch round 0..3
  const int c  = id & 255;
  const int bh = (c & 7) + 8 * r;     // XCD = id%8 = bh&7
  const int v  = c >> 3;              // 0..31

  const int J  = (w >> 1) ^ (r & 1);  // job slot (round-swapped for balance)
  const int wp = w & 1;               // key-tile parity of this wave
  const int qt = (J == 0) ? v : 63 - v;
  const int q0w = qt * 32;

  const __bf16* Qg = Q  + (size_t)bh * T * HD;
  const __bf16* Kg = K  + (size_t)bh * T * HD;
  const __bf16* Vg = Vt + (size_t)bh * HD * T;

  // Q B-fragments: col=q=l31; per k-step st: elements st*16 + hi*8 ..+8
  bf16x8 qfr[4];
  #pragma unroll
  for (int st = 0; st < 4; ++st)
    qfr[st] = *reinterpret_cast<const bf16x8*>(
        Qg + (size_t)(q0w + l31) * HD + st * 16 + hi * 8);

  float m_run = -INFINITY, l_run = 0.f;
  f32x16 oacc0, oacc1;
  #pragma unroll
  for (int i = 0; i < 16; ++i) { oacc0[i] = 0.f; oacc1[i] = 0.f; }

  // K frag (A): row=key=l31, k elems hi*8; V frag (A): row=hd, k elems hi*8
  const __bf16* kbase = Kg + (size_t)l31 * HD + hi * 8;
  const __bf16* vbase = Vg + (size_t)l31 * T + hi * 8;

#define LOADKV(K0, K1, K2, K3, V00, V01, V10, V11, jj)                        \
  do {                                                                        \
    const __bf16* _kp = kbase + (size_t)(jj) * 32 * HD;                       \
    K0 = *reinterpret_cast<const bf16x8*>(_kp);                               \
    K1 = *reinterpret_cast<const bf16x8*>(_kp + 16);                          \
    K2 = *reinterpret_cast<const bf16x8*>(_kp + 32);                          \
    K3 = *reinterpret_cast<const bf16x8*>(_kp + 48);                          \
    const __bf16* _vp = vbase + (size_t)(jj) * 32;                            \
    V00 = *reinterpret_cast<const bf16x8*>(_vp);                              \
    V01 = *reinterpret_cast<const bf16x8*>(_vp + 16);                         \
    V10 = *reinterpret_cast<const bf16x8*>(_vp + (size_t)32 * T);             \
    V11 = *reinterpret_cast<const bf16x8*>(_vp + (size_t)32 * T + 16);        \
  } while (0)

#define TILE(K0, K1, K2, K3, V00, V01, V10, V11, jj)                          \
  do {                                                                        \
    f32x16 sva, svb;                                                          \
    _Pragma("unroll")                                                         \
    for (int _i = 0; _i < 16; ++_i) { sva[_i] = 0.f; svb[_i] = 0.f; }         \
    sva = mfma32(K0, qfr[0], sva);                                            \
    svb = mfma32(K1, qfr[1], svb);                                            \
    sva = mfma32(K2, qfr[2], sva);                                            \
    svb = mfma32(K3, qfr[3], svb);                                            \
    f32x16 sv;                                                                \
    _Pragma("unroll")                                                         \
    for (int _i = 0; _i < 16; ++_i) sv[_i] = sva[_i] + svb[_i];               \
    if ((jj) == qt) { /* diagonal tile: causal mask */                        \
      const int _q = q0w + l31;                                               \
      const int _kb = (jj) * 32 + 4 * hi;                                     \
      _Pragma("unroll")                                                       \
      for (int _r = 0; _r < 16; ++_r) {                                       \
        const int _key = _kb + (_r & 3) + 8 * (_r >> 2);                      \
        if (_key > _q) sv[_r] = -INFINITY;                                    \
      }                                                                       \
    }                                                                         \
    float _mx[8];                                                             \
    _Pragma("unroll")                                                         \
    for (int _i = 0; _i < 8; ++_i) _mx[_i] = fmaxf(sv[_i], sv[_i + 8]);       \
    _Pragma("unroll")                                                         \
    for (int _s = 4; _s > 0; _s >>= 1)                                        \
      _Pragma("unroll")                                                       \
      for (int _i = 0; _i < 4; ++_i)                                          \
        if (_i < _s) _mx[_i] = fmaxf(_mx[_i], _mx[_i + _s]);                  \
    union { float f; unsigned u; } _cv; _cv.f = _mx[0];                       \
    u32x2 _sw = plswap(_cv.u, _cv.u);                                         \
    union { unsigned u; float f; } _c0, _c1; _c0.u = _sw[0]; _c1.u = _sw[1];  \
    const float _pmax = fmaxf(_c0.f, _c1.f);                                  \
    if (__any(_pmax > m_run + 8.f)) {                                         \
      const float _mn = fmaxf(m_run, _pmax);                                  \
      const float _rs = exp2f(m_run - _mn);                                   \
      l_run *= _rs;                                                           \
      _Pragma("unroll")                                                       \
      for (int _i = 0; _i < 16; ++_i) { oacc0[_i] *= _rs; oacc1[_i] *= _rs; } \
      m_run = _mn;                                                            \
    }                                                                         \
    _Pragma("unroll")                                                         \
    for (int _i = 0; _i < 16; ++_i) sv[_i] = exp2f(sv[_i] - m_run);           \
    float _sm[8];                                                             \
    _Pragma("unroll")                                                         \
    for (int _i = 0; _i < 8; ++_i) _sm[_i] = sv[_i] + sv[_i + 8];             \
    _Pragma("unroll")                                                         \
    for (int _s = 4; _s > 0; _s >>= 1)                                        \
      _Pragma("unroll")                                                       \
      for (int _i = 0; _i < 4; ++_i)                                          \
        if (_i < _s) _sm[_i] += _sm[_i + _s];                                 \
    l_run += _sm[0];                                                          \
    unsigned _cp[8];                                                          \
    _Pragma("unroll")                                                         \
    for (int _m = 0; _m < 4; ++_m) {                                          \
      _cp[2 * _m]     = cvtpk(sv[4 * _m],     sv[4 * _m + 1]);                \
      _cp[2 * _m + 1] = cvtpk(sv[4 * _m + 2], sv[4 * _m + 3]);                \
    }                                                                         \
    {                                                                         \
      u32x2 _r0 = plswap(_cp[0], _cp[2]);                                     \
      u32x2 _r1 = plswap(_cp[1], _cp[3]);                                     \
      union { u32x4 u; bf16x8 v; } _pu;                                       \
      _pu.u = (u32x4){_r0[0], _r1[0], _r0[1], _r1[1]};                        \
      oacc0 = mfma32(V00, _pu.v, oacc0);                                      \
      oacc1 = mfma32(V10, _pu.v, oacc1);                                      \
    }                                                                         \
    {                                                                         \
      u32x2 _r0 = plswap(_cp[4], _cp[6]);                                     \
      u32x2 _r1 = plswap(_cp[5], _cp[7]);                                     \
      union { u32x4 u; bf16x8 v; } _pu;                                       \
      _pu.u = (u32x4){_r0[0], _r1[0], _r0[1], _r1[1]};                        \
      oacc0 = mfma32(V01, _pu.v, oacc0);                                      \
      oacc1 = mfma32(V11, _pu.v, oacc1);                                      \
    }                                                                         \
  } while (0)

  bf16x8 kA0, kA1, kA2, kA3, vA00, vA01, vA10, vA11;
  bf16x8 kB0, kB1, kB2, kB3, vB00, vB01, vB10, vB11;

  // This wave's tiles: wp, wp+2, ..., <= qt  (register-pipelined 1 ahead)
  int jj = wp;
  if (jj <= qt) {
    LOADKV(kA0, kA1, kA2, kA3, vA00, vA01, vA10, vA11, jj);
    #pragma unroll 1
    for (;;) {
      if (jj + 2 <= qt)
        LOADKV(kB0, kB1, kB2, kB3, vB00, vB01, vB10, vB11, jj + 2);
      TILE(kA0, kA1, kA2, kA3, vA00, vA01, vA10, vA11, jj);
      if (jj + 2 > qt) break;
      if (jj + 4 <= qt)
        LOADKV(kA0, kA1, kA2, kA3, vA00, vA01, vA10, vA11, jj + 4);
      TILE(kB0, kB1, kB2, kB3, vB00, vB01, vB10, vB11, jj + 2);
      if (jj + 4 > qt) break;
      jj += 4;
    }
  }
#undef TILE
#undef LOADKV

  // ---- split-K merge: parity-1 wave publishes partials, parity-0 merges ---
  float* row = &Mrg[J][lane][0];
  if (wp == 1) {
    #pragma unroll
    for (int i = 0; i < 16; ++i) row[i]      = oacc0[i];
    #pragma unroll
    for (int i = 0; i < 16; ++i) row[16 + i] = oacc1[i];
    row[32] = m_run;
    row[33] = l_run;
  }
  __syncthreads();
  if (wp == 0) {
    const float mB = row[32], lB = row[33];
    const float mS = fmaxf(m_run, mB);
    const float sA = exp2f(m_run - mS);
    const float sB = exp2f(mB - mS);
    float l_lane = l_run * sA + lB * sB;
    const float l_tot = l_lane + __shfl_xor(l_lane, 32);
    const float inv = 1.f / l_tot;

    const int b = bh >> 4, h = bh & 15;
    const int q_abs = q0w + l31;
    const size_t rowbase = ((size_t)(b * T + q_abs)) * 1024 + h * 64;
    #pragma unroll
    for (int rg = 0; rg < 4; ++rg) {
      bf16x4 o0, o1;
      #pragma unroll
      for (int rr = 0; rr < 4; ++rr) {
        const int i = rg * 4 + rr;
        o0[rr] = (__bf16)((oacc0[i] * sA + row[i]      * sB) * inv);
        o1[rr] = (__bf16)((oacc1[i] * sA + row[16 + i] * sB) * inv);
      }
      *reinterpret_cast<bf16x4*>(&Ob[rowbase + rg * 8 + hi * 4])      = o0;
      *reinterpret_cast<bf16x4*>(&Ob[rowbase + 32 + rg * 8 + hi * 4]) = o1;
    }
  }
}

// ---------------------------------------------------------------------------
extern "C" void kernel_launch(void* const* d_in, const int* in_sizes, int n_in,
                              void* d_out, int out_size, void* d_ws, size_t ws_size,
                              hipStream_t stream) {
  const float* x    = (const float*)d_in[0];
  const float* cosT = (const float*)d_in[1];
  const float* sinT = (const float*)d_in[2];
  // d_in[3] = mask (causal, analytic)
  const float* wq   = (const float*)d_in[4];
  const float* wk   = (const float*)d_in[5];
  const float* wv   = (const float*)d_in[6];
  const float* wo   = (const float*)d_in[7];
  float* out = (float*)d_out;

  __bf16* xb   = (__bf16*)d_ws;
  __bf16* wqb  = xb  + XSZ;
  __bf16* wkb  = wqb + WSZ;
  __bf16* wvb  = wkb + WSZ;
  __bf16* wob  = wvb + WSZ;
  __bf16* Qh   = wob + WSZ;      // [bh][t][hd]  (pre-scaled by 0.125*log2e)
  __bf16* Kh   = Qh  + XSZ;      // [bh][t][hd]
  __bf16* Vth  = Kh  + XSZ;      // [bh][hd][t]
  __bf16* attb = Vth + XSZ;      // [M][1024]

  cvt_all<<<(XSZ + 4 * WSZ) / 8 / 256, 256, 0, stream>>>(x, wq, wk, wv, wo, xb);

  gemm_mfma<1><<<dim3(24, 32), 512, 0, stream>>>(
      xb, wqb, wkb, wvb, cosT, sinT, Qh, Kh, Vth);

  attn_v11<<<dim3(1024), 256, 0, stream>>>(Qh, Kh, Vth, attb);

  gemm_mfma<0><<<dim3(8, 32), 512, 0, stream>>>(
      attb, wob, nullptr, nullptr, nullptr, nullptr, out, nullptr, nullptr);
}

// Round 14
// 158.786 us; speedup vs baseline: 1.2907x; 1.0355x over previous
//
#include <hip/hip_runtime.h>
#include <math.h>

constexpr int D  = 1024;
constexpr int H  = 16;
constexpr int HD = 64;
constexpr int B  = 2;
constexpr int T  = 2048;
constexpr int M  = B * T;   // 4096

constexpr size_t XSZ = (size_t)M * D;   // 4,194,304
constexpr size_t WSZ = (size_t)D * D;   // 1,048,576

typedef float  f32x4   __attribute__((ext_vector_type(4)));
typedef float  f32x16  __attribute__((ext_vector_type(16)));
typedef __bf16 bf16x8  __attribute__((ext_vector_type(8)));
typedef __bf16 bf16x4  __attribute__((ext_vector_type(4)));
typedef unsigned u32x2 __attribute__((ext_vector_type(2)));
typedef unsigned u32x4 __attribute__((ext_vector_type(4)));

static __device__ inline f32x4 mfma16(bf16x8 a, bf16x8 b, f32x4 c) {
  return __builtin_amdgcn_mfma_f32_16x16x32_bf16(a, b, c, 0, 0, 0);
}
static __device__ inline f32x16 mfma32(bf16x8 a, bf16x8 b, f32x16 c) {
  return __builtin_amdgcn_mfma_f32_32x32x16_bf16(a, b, c, 0, 0, 0);
}
// pack two f32 -> u32 of 2 bf16 (lo = a, hi = b); no builtin on gfx950
static __device__ inline unsigned cvtpk(float a, float b) {
  unsigned r;
  asm("v_cvt_pk_bf16_f32 %0, %1, %2" : "=v"(r) : "v"(a), "v"(b));
  return r;
}
static __device__ inline u32x2 plswap(unsigned a, unsigned b) {
  return __builtin_amdgcn_permlane32_swap(a, b, false, false);
}
// async global->LDS, 16B per lane (dest = wave-uniform base + lane*16)
static __device__ inline void gload16(const __bf16* g, __bf16* l) {
  __builtin_amdgcn_global_load_lds(
      (const __attribute__((address_space(1))) void*)g,
      (__attribute__((address_space(3))) void*)l, 16, 0, 0);
}

// ---------------------------------------------------------------------------
// Fused fp32->bf16 convert of x + 4 weights into contiguous bf16 workspace.
// ---------------------------------------------------------------------------
__global__ __launch_bounds__(256)
void cvt_all(const float* __restrict__ x, const float* __restrict__ wq,
             const float* __restrict__ wk, const float* __restrict__ wv,
             const float* __restrict__ wo, __bf16* __restrict__ out) {
  size_t idx = ((size_t)blockIdx.x * 256 + threadIdx.x) * 8;
  const float* src;
  if      (idx < XSZ)            src = x  + idx;
  else if (idx < XSZ + WSZ)      src = wq + (idx - XSZ);
  else if (idx < XSZ + 2 * WSZ)  src = wk + (idx - XSZ - WSZ);
  else if (idx < XSZ + 3 * WSZ)  src = wv + (idx - XSZ - 2 * WSZ);
  else                           src = wo + (idx - XSZ - 3 * WSZ);
  float4 a = *reinterpret_cast<const float4*>(src);
  float4 b = *reinterpret_cast<const float4*>(src + 4);
  bf16x8 o;
  o[0] = (__bf16)a.x; o[1] = (__bf16)a.y; o[2] = (__bf16)a.z; o[3] = (__bf16)a.w;
  o[4] = (__bf16)b.x; o[5] = (__bf16)b.y; o[6] = (__bf16)b.z; o[7] = (__bf16)b.w;
  *reinterpret_cast<bf16x8*>(out + idx) = o;
}

// ---------------------------------------------------------------------------
// MFMA GEMM — exact m97 geometry (verified 874-912 TF in the guide):
// 128x128 tile, BK=64, 256 threads = 4 waves (2x2), per-wave 64x64,
// acc[4][4], 32 MFMA per K-iter, global_load_lds staging (8 chunks/thread).
// MODE 1: fused QKV; Q gets softmax-scale (0.125*log2e) folded into RoPE.
// MODE 0: single GEMM (wo), fp32 out.
// ---------------------------------------------------------------------------
template<int MODE>
__global__ __launch_bounds__(256)
void gemm_mfma(const __bf16* __restrict__ A,
               const __bf16* __restrict__ W0, const __bf16* __restrict__ W1,
               const __bf16* __restrict__ W2,
               const float* __restrict__ cosT, const float* __restrict__ sinT,
               void* __restrict__ out0, void* __restrict__ out1,
               void* __restrict__ out2) {
  __shared__ __bf16 As[128 * 64];
  __shared__ __bf16 Bs[128 * 64];

  const int tid  = threadIdx.x;
  const int lane = tid & 63;
  const int w    = tid >> 6;     // 0..3
  const int wm   = w >> 1;       // 0..1 (64 rows each)
  const int wn   = w & 1;        // 0..1 (64 cols each)
  const int l15  = lane & 15, lg = lane >> 4;
  const int m0   = blockIdx.y * 128;

  int which, n0;
  const __bf16* Bw;
  if (MODE == 1) {
    which = blockIdx.x >> 3;
    n0 = (blockIdx.x & 7) * 128;
    Bw = which == 0 ? W0 : which == 1 ? W1 : W2;
  } else {
    which = 0;
    n0 = blockIdx.x * 128;
    Bw = W0;
  }

  f32x4 acc[4][4];
  #pragma unroll
  for (int i = 0; i < 4; ++i)
    #pragma unroll
    for (int j = 0; j < 4; ++j) acc[i][j] = (f32x4){0.f, 0.f, 0.f, 0.f};

  const int r0 = tid >> 3;          // 0..31
  const int c0 = (tid & 7) * 8;     // 0..56

  for (int k0 = 0; k0 < 1024; k0 += 64) {
    #pragma unroll
    for (int i = 0; i < 4; ++i) {
      gload16(A  + (size_t)(m0 + r0 + 32 * i) * 1024 + k0 + c0,
              As + (tid + 256 * i) * 8);
      gload16(Bw + (size_t)(n0 + r0 + 32 * i) * 1024 + k0 + c0,
              Bs + (tid + 256 * i) * 8);
    }
    __syncthreads();   // drains vmcnt -> LDS tiles ready

    #pragma unroll
    for (int ks = 0; ks < 2; ++ks) {
      bf16x8 af[4], bfr[4];
      #pragma unroll
      for (int mt = 0; mt < 4; ++mt)
        af[mt] = *reinterpret_cast<const bf16x8*>(
            &As[(wm * 64 + mt * 16 + l15) * 64 + ks * 32 + lg * 8]);
      #pragma unroll
      for (int nt = 0; nt < 4; ++nt)
        bfr[nt] = *reinterpret_cast<const bf16x8*>(
            &Bs[(wn * 64 + nt * 16 + l15) * 64 + ks * 32 + lg * 8]);
      #pragma unroll
      for (int mt = 0; mt < 4; ++mt)
        #pragma unroll
        for (int nt = 0; nt < 4; ++nt)
          acc[mt][nt] = mfma16(af[mt], bfr[nt], acc[mt][nt]);
    }
    __syncthreads();
  }

  // Frag: n = n0 + wn*64 + nt*16 + l15 ; m = m0 + wm*64 + mt*16 + lg*4 + r
  if (MODE == 0) {
    float* o = (float*)out0;
    #pragma unroll
    for (int mt = 0; mt < 4; ++mt) {
      const int mb = m0 + wm * 64 + mt * 16 + lg * 4;
      #pragma unroll
      for (int nt = 0; nt < 4; ++nt) {
        const int n = n0 + wn * 64 + nt * 16 + l15;
        #pragma unroll
        for (int r = 0; r < 4; ++r)
          o[(size_t)(mb + r) * 1024 + n] = acc[mt][nt][r];
      }
    }
  } else if (which < 2) {
    // Q or K: RoPE fused; Q additionally scaled by 0.125*log2(e).
    // Per-wave n range = one full head (64 cols); pair (hd, hd+32) = (nt, nt+2).
    __bf16* dst = which == 0 ? (__bf16*)out0 : (__bf16*)out1;
    const float qs = (which == 0) ? 0.180336880f : 1.0f;
    const int h = (n0 + wn * 64) >> 6;
    #pragma unroll
    for (int mt = 0; mt < 4; ++mt) {
      const int tb   = m0 + wm * 64 + mt * 16 + lg * 4;
      const int bb   = tb >> 11;
      const int tloc = tb & 2047;
      #pragma unroll
      for (int r = 0; r < 4; ++r) {
        const int t = tloc + r;
        #pragma unroll
        for (int nt = 0; nt < 2; ++nt) {
          const int hd = nt * 16 + l15;
          const float c = cosT[t * HD + hd];
          const float s = sinT[t * HD + hd];
          const float v1 = acc[mt][nt][r];
          const float v2 = acc[mt][nt + 2][r];
          const size_t base = (((size_t)(bb * H + h)) * T + t) * HD;
          dst[base + hd]      = (__bf16)((v1 * c - v2 * s) * qs);
          dst[base + hd + 32] = (__bf16)((v2 * c + v1 * s) * qs);
        }
      }
    }
  } else {
    // V: transposed store [bh][hd][t]
    __bf16* dst = (__bf16*)out2;
    const int h = (n0 + wn * 64) >> 6;
    #pragma unroll
    for (int mt = 0; mt < 4; ++mt) {
      const int tb = m0 + wm * 64 + mt * 16 + lg * 4;
      const int bb = tb >> 11;
      const int t0 = tb & 2047;
      #pragma unroll
      for (int nt = 0; nt < 4; ++nt) {
        const int hd = nt * 16 + l15;
        bf16x4 ov;
        #pragma unroll
        for (int r = 0; r < 4; ++r) ov[r] = (__bf16)acc[mt][nt][r];
        *reinterpret_cast<bf16x4*>(
            &dst[(((size_t)(bb * H + h)) * HD + hd) * T + t0]) = ov;
      }
    }
  }
}

// ---------------------------------------------------------------------------
// attn_v9 (verbatim from round 11 — best measured attn: 76 µs).
// Barrier-free, LDS-free, register-pipelined; XCD = bh&7 locality.
// ---------------------------------------------------------------------------
__global__ __launch_bounds__(256, 2)
void attn_v9(const __bf16* __restrict__ Q, const __bf16* __restrict__ K,
             const __bf16* __restrict__ Vt, __bf16* __restrict__ Ob) {
  const int tid  = threadIdx.x;
  const int lane = tid & 63;
  const int w    = tid >> 6;          // 0..3
  const int l31  = lane & 31;
  const int hi   = lane >> 5;         // 0..1
  const int bx   = blockIdx.x;        // 0..15
  const int by   = blockIdx.y;        // 0..31
  const int bh   = (bx & 7) + 8 * (by >> 3);   // XCD = bh&7
  const int x    = (bx >> 3) + 2 * (by & 7);   // 0..15

  const int wi = (bh < 16) ? w : (w ^ 1);
  const int qt = (wi == 0) ? 2 * x : (wi == 1) ? 63 - 2 * x
               : (wi == 2) ? 2 * x + 1 : 62 - 2 * x;
  const int q0w    = qt * 32;
  const int ntiles = qt + 1;

  const __bf16* Qg = Q  + (size_t)bh * T * HD;
  const __bf16* Kg = K  + (size_t)bh * T * HD;
  const __bf16* Vg = Vt + (size_t)bh * HD * T;

  // Q B-fragments: col=q=l31; per k-step st: elements st*16 + hi*8 ..+8
  bf16x8 qfr[4];
  #pragma unroll
  for (int st = 0; st < 4; ++st)
    qfr[st] = *reinterpret_cast<const bf16x8*>(
        Qg + (size_t)(q0w + l31) * HD + st * 16 + hi * 8);

  float m_run = -INFINITY, l_run = 0.f;
  f32x16 oacc0, oacc1;
  #pragma unroll
  for (int i = 0; i < 16; ++i) { oacc0[i] = 0.f; oacc1[i] = 0.f; }

  // K frag (A): row=key=l31, k elems hi*8; V frag (A): row=hd, k elems hi*8
  const __bf16* kbase = Kg + (size_t)l31 * HD + hi * 8;
  const __bf16* vbase = Vg + (size_t)l31 * T + hi * 8;

#define LOADKV(K0, K1, K2, K3, V00, V01, V10, V11, jj)                        \
  do {                                                                        \
    const __bf16* _kp = kbase + (size_t)(jj) * 32 * HD;                       \
    K0 = *reinterpret_cast<const bf16x8*>(_kp);                               \
    K1 = *reinterpret_cast<const bf16x8*>(_kp + 16);                          \
    K2 = *reinterpret_cast<const bf16x8*>(_kp + 32);                          \
    K3 = *reinterpret_cast<const bf16x8*>(_kp + 48);                          \
    const __bf16* _vp = vbase + (size_t)(jj) * 32;                            \
    V00 = *reinterpret_cast<const bf16x8*>(_vp);                              \
    V01 = *reinterpret_cast<const bf16x8*>(_vp + 16);                         \
    V10 = *reinterpret_cast<const bf16x8*>(_vp + (size_t)32 * T);             \
    V11 = *reinterpret_cast<const bf16x8*>(_vp + (size_t)32 * T + 16);        \
  } while (0)

#define TILE(K0, K1, K2, K3, V00, V01, V10, V11, jj)                          \
  do {                                                                        \
    f32x16 sva, svb;                                                          \
    _Pragma("unroll")                                                         \
    for (int _i = 0; _i < 16; ++_i) { sva[_i] = 0.f; svb[_i] = 0.f; }         \
    sva = mfma32(K0, qfr[0], sva);                                            \
    svb = mfma32(K1, qfr[1], svb);                                            \
    sva = mfma32(K2, qfr[2], sva);                                            \
    svb = mfma32(K3, qfr[3], svb);                                            \
    f32x16 sv;                                                                \
    _Pragma("unroll")                                                         \
    for (int _i = 0; _i < 16; ++_i) sv[_i] = sva[_i] + svb[_i];               \
    if ((jj) == qt) { /* diagonal tile: causal mask */                        \
      const int _q = q0w + l31;                                               \
      const int _kb = (jj) * 32 + 4 * hi;                                     \
      _Pragma("unroll")                                                       \
      for (int _r = 0; _r < 16; ++_r) {                                       \
        const int _key = _kb + (_r & 3) + 8 * (_r >> 2);                      \
        if (_key > _q) sv[_r] = -INFINITY;                                    \
      }                                                                       \
    }                                                                         \
    float _mx[8];                                                             \
    _Pragma("unroll")                                                         \
    for (int _i = 0; _i < 8; ++_i) _mx[_i] = fmaxf(sv[_i], sv[_i + 8]);       \
    _Pragma("unroll")                                                         \
    for (int _s = 4; _s > 0; _s >>= 1)                                        \
      _Pragma("unroll")                                                       \
      for (int _i = 0; _i < 4; ++_i)                                          \
        if (_i < _s) _mx[_i] = fmaxf(_mx[_i], _mx[_i + _s]);                  \
    union { float f; unsigned u; } _cv; _cv.f = _mx[0];                       \
    u32x2 _sw = plswap(_cv.u, _cv.u);                                         \
    union { unsigned u; float f; } _c0, _c1; _c0.u = _sw[0]; _c1.u = _sw[1];  \
    const float _pmax = fmaxf(_c0.f, _c1.f);                                  \
    if (__any(_pmax > m_run + 8.f)) {                                         \
      const float _mn = fmaxf(m_run, _pmax);                                  \
      const float _rs = exp2f(m_run - _mn);                                   \
      l_run *= _rs;                                                           \
      _Pragma("unroll")                                                       \
      for (int _i = 0; _i < 16; ++_i) { oacc0[_i] *= _rs; oacc1[_i] *= _rs; } \
      m_run = _mn;                                                            \
    }                                                                         \
    _Pragma("unroll")                                                         \
    for (int _i = 0; _i < 16; ++_i) sv[_i] = exp2f(sv[_i] - m_run);           \
    float _sm[8];                                                             \
    _Pragma("unroll")                                                         \
    for (int _i = 0; _i < 8; ++_i) _sm[_i] = sv[_i] + sv[_i + 8];             \
    _Pragma("unroll")                                                         \
    for (int _s = 4; _s > 0; _s >>= 1)                                        \
      _Pragma("unroll")                                                       \
      for (int _i = 0; _i < 4; ++_i)                                          \
        if (_i < _s) _sm[_i] += _sm[_i + _s];                                 \
    l_run += _sm[0];                                                          \
    unsigned _cp[8];                                                          \
    _Pragma("unroll")                                                         \
    for (int _m = 0; _m < 4; ++_m) {                                          \
      _cp[2 * _m]     = cvtpk(sv[4 * _m],     sv[4 * _m + 1]);                \
      _cp[2 * _m + 1] = cvtpk(sv[4 * _m + 2], sv[4 * _m + 3]);                \
    }                                                                         \
    {                                                                         \
      u32x2 _r0 = plswap(_cp[0], _cp[2]);                                     \
      u32x2 _r1 = plswap(_cp[1], _cp[3]);                                     \
      union { u32x4 u; bf16x8 v; } _pu;                                       \
      _pu.u = (u32x4){_r0[0], _r1[0], _r0[1], _r1[1]};                        \
      oacc0 = mfma32(V00, _pu.v, oacc0);                                      \
      oacc1 = mfma32(V10, _pu.v, oacc1);                                      \
    }                                                                         \
    {                                                                         \
      u32x2 _r0 = plswap(_cp[4], _cp[6]);                                     \
      u32x2 _r1 = plswap(_cp[5], _cp[7]);                                     \
      union { u32x4 u; bf16x8 v; } _pu;                                       \
      _pu.u = (u32x4){_r0[0], _r1[0], _r0[1], _r1[1]};                        \
      oacc0 = mfma32(V01, _pu.v, oacc0);                                      \
      oacc1 = mfma32(V11, _pu.v, oacc1);                                      \
    }                                                                         \
  } while (0)

  bf16x8 kA0, kA1, kA2, kA3, vA00, vA01, vA10, vA11;
  bf16x8 kB0, kB1, kB2, kB3, vB00, vB01, vB10, vB11;

  LOADKV(kA0, kA1, kA2, kA3, vA00, vA01, vA10, vA11, 0);
  int j = 0;
  #pragma unroll 1
  for (;;) {
    if (j + 1 < ntiles)
      LOADKV(kB0, kB1, kB2, kB3, vB00, vB01, vB10, vB11, j + 1);
    TILE(kA0, kA1, kA2, kA3, vA00, vA01, vA10, vA11, j);
    if (j + 1 >= ntiles) break;
    if (j + 2 < ntiles)
      LOADKV(kA0, kA1, kA2, kA3, vA00, vA01, vA10, vA11, j + 2);
    TILE(kB0, kB1, kB2, kB3, vB00, vB01, vB10, vB11, j + 1);
    if (j + 2 >= ntiles) break;
    j += 2;
  }
#undef TILE
#undef LOADKV

  // ---- epilogue: O rows hd = (reg&3)+8*(reg>>2)+4hi, q col = l31 ----
  const float l_tot = l_run + __shfl_xor(l_run, 32);
  const float inv = 1.f / l_tot;
  const int b = bh >> 4, h = bh & 15;
  const int q_abs = q0w + l31;
  const size_t rowbase = ((size_t)(b * T + q_abs)) * 1024 + h * 64;
  #pragma unroll
  for (int rg = 0; rg < 4; ++rg) {
    bf16x4 o0, o1;
    #pragma unroll
    for (int r = 0; r < 4; ++r) {
      o0[r] = (__bf16)(oacc0[rg * 4 + r] * inv);
      o1[r] = (__bf16)(oacc1[rg * 4 + r] * inv);
    }
    *reinterpret_cast<bf16x4*>(&Ob[rowbase + rg * 8 + hi * 4])      = o0;
    *reinterpret_cast<bf16x4*>(&Ob[rowbase + 32 + rg * 8 + hi * 4]) = o1;
  }
}

// ---------------------------------------------------------------------------
extern "C" void kernel_launch(void* const* d_in, const int* in_sizes, int n_in,
                              void* d_out, int out_size, void* d_ws, size_t ws_size,
                              hipStream_t stream) {
  const float* x    = (const float*)d_in[0];
  const float* cosT = (const float*)d_in[1];
  const float* sinT = (const float*)d_in[2];
  // d_in[3] = mask (causal, analytic)
  const float* wq   = (const float*)d_in[4];
  const float* wk   = (const float*)d_in[5];
  const float* wv   = (const float*)d_in[6];
  const float* wo   = (const float*)d_in[7];
  float* out = (float*)d_out;

  __bf16* xb   = (__bf16*)d_ws;
  __bf16* wqb  = xb  + XSZ;
  __bf16* wkb  = wqb + WSZ;
  __bf16* wvb  = wkb + WSZ;
  __bf16* wob  = wvb + WSZ;
  __bf16* Qh   = wob + WSZ;      // [bh][t][hd]  (pre-scaled by 0.125*log2e)
  __bf16* Kh   = Qh  + XSZ;      // [bh][t][hd]
  __bf16* Vth  = Kh  + XSZ;      // [bh][hd][t]
  __bf16* attb = Vth + XSZ;      // [M][1024]

  cvt_all<<<(XSZ + 4 * WSZ) / 8 / 256, 256, 0, stream>>>(x, wq, wk, wv, wo, xb);

  gemm_mfma<1><<<dim3(24, 32), 256, 0, stream>>>(
      xb, wqb, wkb, wvb, cosT, sinT, Qh, Kh, Vth);

  attn_v9<<<dim3(16, 32), 256, 0, stream>>>(Qh, Kh, Vth, attb);

  gemm_mfma<0><<<dim3(8, 32), 256, 0, stream>>>(
      attb, wob, nullptr, nullptr, nullptr, nullptr, out, nullptr, nullptr);
}

// Round 15
// 156.292 us; speedup vs baseline: 1.3113x; 1.0160x over previous
//
#include <hip/hip_runtime.h>
#include <math.h>

constexpr int D  = 1024;
constexpr int H  = 16;
constexpr int HD = 64;
constexpr int B  = 2;
constexpr int T  = 2048;
constexpr int M  = B * T;   // 4096

constexpr size_t XSZ = (size_t)M * D;   // 4,194,304
constexpr size_t WSZ = (size_t)D * D;   // 1,048,576

typedef float  f32x4   __attribute__((ext_vector_type(4)));
typedef float  f32x16  __attribute__((ext_vector_type(16)));
typedef __bf16 bf16x8  __attribute__((ext_vector_type(8)));
typedef __bf16 bf16x4  __attribute__((ext_vector_type(4)));
typedef unsigned u32x2 __attribute__((ext_vector_type(2)));
typedef unsigned u32x4 __attribute__((ext_vector_type(4)));

static __device__ inline f32x4 mfma16(bf16x8 a, bf16x8 b, f32x4 c) {
  return __builtin_amdgcn_mfma_f32_16x16x32_bf16(a, b, c, 0, 0, 0);
}
static __device__ inline f32x16 mfma32(bf16x8 a, bf16x8 b, f32x16 c) {
  return __builtin_amdgcn_mfma_f32_32x32x16_bf16(a, b, c, 0, 0, 0);
}
// pack two f32 -> u32 of 2 bf16 (lo = a, hi = b); no builtin on gfx950
static __device__ inline unsigned cvtpk(float a, float b) {
  unsigned r;
  asm("v_cvt_pk_bf16_f32 %0, %1, %2" : "=v"(r) : "v"(a), "v"(b));
  return r;
}
static __device__ inline u32x2 plswap(unsigned a, unsigned b) {
  return __builtin_amdgcn_permlane32_swap(a, b, false, false);
}
// async global->LDS, 16B per lane (dest = wave-uniform base + lane*16)
static __device__ inline void gload16(const __bf16* g, __bf16* l) {
  __builtin_amdgcn_global_load_lds(
      (const __attribute__((address_space(1))) void*)g,
      (__attribute__((address_space(3))) void*)l, 16, 0, 0);
}

// ---------------------------------------------------------------------------
// Fused fp32->bf16 convert of x + 4 weights into contiguous bf16 workspace.
// ---------------------------------------------------------------------------
__global__ __launch_bounds__(256)
void cvt_all(const float* __restrict__ x, const float* __restrict__ wq,
             const float* __restrict__ wk, const float* __restrict__ wv,
             const float* __restrict__ wo, __bf16* __restrict__ out) {
  size_t idx = ((size_t)blockIdx.x * 256 + threadIdx.x) * 8;
  const float* src;
  if      (idx < XSZ)            src = x  + idx;
  else if (idx < XSZ + WSZ)      src = wq + (idx - XSZ);
  else if (idx < XSZ + 2 * WSZ)  src = wk + (idx - XSZ - WSZ);
  else if (idx < XSZ + 3 * WSZ)  src = wv + (idx - XSZ - 2 * WSZ);
  else                           src = wo + (idx - XSZ - 3 * WSZ);
  float4 a = *reinterpret_cast<const float4*>(src);
  float4 b = *reinterpret_cast<const float4*>(src + 4);
  bf16x8 o;
  o[0] = (__bf16)a.x; o[1] = (__bf16)a.y; o[2] = (__bf16)a.z; o[3] = (__bf16)a.w;
  o[4] = (__bf16)b.x; o[5] = (__bf16)b.y; o[6] = (__bf16)b.z; o[7] = (__bf16)b.w;
  *reinterpret_cast<bf16x8*>(out + idx) = o;
}

// ---------------------------------------------------------------------------
// MFMA GEMM — m97 geometry: 128x128 tile, BK=64, 256 threads = 4 waves (2x2),
// per-wave 64x64, acc[4][4], 32 MFMA per K-iter, global_load_lds staging.
// MODE 1: fused QKV; Q gets softmax-scale (0.125*log2e) folded into RoPE.
// MODE 0: single GEMM (wo), fp32 out.
// ---------------------------------------------------------------------------
template<int MODE>
__global__ __launch_bounds__(256)
void gemm_mfma(const __bf16* __restrict__ A,
               const __bf16* __restrict__ W0, const __bf16* __restrict__ W1,
               const __bf16* __restrict__ W2,
               const float* __restrict__ cosT, const float* __restrict__ sinT,
               void* __restrict__ out0, void* __restrict__ out1,
               void* __restrict__ out2) {
  __shared__ __bf16 As[128 * 64];
  __shared__ __bf16 Bs[128 * 64];

  const int tid  = threadIdx.x;
  const int lane = tid & 63;
  const int w    = tid >> 6;     // 0..3
  const int wm   = w >> 1;       // 0..1 (64 rows each)
  const int wn   = w & 1;        // 0..1 (64 cols each)
  const int l15  = lane & 15, lg = lane >> 4;
  const int m0   = blockIdx.y * 128;

  int which, n0;
  const __bf16* Bw;
  if (MODE == 1) {
    which = blockIdx.x >> 3;
    n0 = (blockIdx.x & 7) * 128;
    Bw = which == 0 ? W0 : which == 1 ? W1 : W2;
  } else {
    which = 0;
    n0 = blockIdx.x * 128;
    Bw = W0;
  }

  f32x4 acc[4][4];
  #pragma unroll
  for (int i = 0; i < 4; ++i)
    #pragma unroll
    for (int j = 0; j < 4; ++j) acc[i][j] = (f32x4){0.f, 0.f, 0.f, 0.f};

  const int r0 = tid >> 3;          // 0..31
  const int c0 = (tid & 7) * 8;     // 0..56

  for (int k0 = 0; k0 < 1024; k0 += 64) {
    #pragma unroll
    for (int i = 0; i < 4; ++i) {
      gload16(A  + (size_t)(m0 + r0 + 32 * i) * 1024 + k0 + c0,
              As + (tid + 256 * i) * 8);
      gload16(Bw + (size_t)(n0 + r0 + 32 * i) * 1024 + k0 + c0,
              Bs + (tid + 256 * i) * 8);
    }
    __syncthreads();   // drains vmcnt -> LDS tiles ready

    #pragma unroll
    for (int ks = 0; ks < 2; ++ks) {
      bf16x8 af[4], bfr[4];
      #pragma unroll
      for (int mt = 0; mt < 4; ++mt)
        af[mt] = *reinterpret_cast<const bf16x8*>(
            &As[(wm * 64 + mt * 16 + l15) * 64 + ks * 32 + lg * 8]);
      #pragma unroll
      for (int nt = 0; nt < 4; ++nt)
        bfr[nt] = *reinterpret_cast<const bf16x8*>(
            &Bs[(wn * 64 + nt * 16 + l15) * 64 + ks * 32 + lg * 8]);
      #pragma unroll
      for (int mt = 0; mt < 4; ++mt)
        #pragma unroll
        for (int nt = 0; nt < 4; ++nt)
          acc[mt][nt] = mfma16(af[mt], bfr[nt], acc[mt][nt]);
    }
    __syncthreads();
  }

  // Frag: n = n0 + wn*64 + nt*16 + l15 ; m = m0 + wm*64 + mt*16 + lg*4 + r
  if (MODE == 0) {
    float* o = (float*)out0;
    #pragma unroll
    for (int mt = 0; mt < 4; ++mt) {
      const int mb = m0 + wm * 64 + mt * 16 + lg * 4;
      #pragma unroll
      for (int nt = 0; nt < 4; ++nt) {
        const int n = n0 + wn * 64 + nt * 16 + l15;
        #pragma unroll
        for (int r = 0; r < 4; ++r)
          o[(size_t)(mb + r) * 1024 + n] = acc[mt][nt][r];
      }
    }
  } else if (which < 2) {
    // Q or K: RoPE fused; Q additionally scaled by 0.125*log2(e).
    __bf16* dst = which == 0 ? (__bf16*)out0 : (__bf16*)out1;
    const float qs = (which == 0) ? 0.180336880f : 1.0f;
    const int h = (n0 + wn * 64) >> 6;
    #pragma unroll
    for (int mt = 0; mt < 4; ++mt) {
      const int tb   = m0 + wm * 64 + mt * 16 + lg * 4;
      const int bb   = tb >> 11;
      const int tloc = tb & 2047;
      #pragma unroll
      for (int r = 0; r < 4; ++r) {
        const int t = tloc + r;
        #pragma unroll
        for (int nt = 0; nt < 2; ++nt) {
          const int hd = nt * 16 + l15;
          const float c = cosT[t * HD + hd];
          const float s = sinT[t * HD + hd];
          const float v1 = acc[mt][nt][r];
          const float v2 = acc[mt][nt + 2][r];
          const size_t base = (((size_t)(bb * H + h)) * T + t) * HD;
          dst[base + hd]      = (__bf16)((v1 * c - v2 * s) * qs);
          dst[base + hd + 32] = (__bf16)((v2 * c + v1 * s) * qs);
        }
      }
    }
  } else {
    // V: transposed store [bh][hd][t]
    __bf16* dst = (__bf16*)out2;
    const int h = (n0 + wn * 64) >> 6;
    #pragma unroll
    for (int mt = 0; mt < 4; ++mt) {
      const int tb = m0 + wm * 64 + mt * 16 + lg * 4;
      const int bb = tb >> 11;
      const int t0 = tb & 2047;
      #pragma unroll
      for (int nt = 0; nt < 4; ++nt) {
        const int hd = nt * 16 + l15;
        bf16x4 ov;
        #pragma unroll
        for (int r = 0; r < 4; ++r) ov[r] = (__bf16)acc[mt][nt][r];
        *reinterpret_cast<bf16x4*>(
            &dst[(((size_t)(bb * H + h)) * HD + hd) * T + t0]) = ov;
      }
    }
  }
}

// ---------------------------------------------------------------------------
// attn_v12: v9 structure with 64-key tiles (one softmax pass per 64 keys).
// Changes vs v9 (75.5 µs, VALUBusy 30%/MfmaUtil 9%):
//  - hoisted zero f32x16 (zv) as MFMA C-in: kills 32 v_mov/32-keys of init
//  - one max tree + pmax permlane + __any + rescale + sum tree per 64 keys
//  - K double-buffered 1 tile ahead; V issued at tile top, used ~400cy later
//  - mask only on the last tile (NT = qt/2+1; fully-masked half -> zeros)
// Per-SIMD balance: wave pairs {2x,63-2x}: NT sums to 33 tiles. XCD = bh&7.
// ---------------------------------------------------------------------------
__global__ __launch_bounds__(256, 2)
void attn_v12(const __bf16* __restrict__ Q, const __bf16* __restrict__ K,
              const __bf16* __restrict__ Vt, __bf16* __restrict__ Ob) {
  const int tid  = threadIdx.x;
  const int lane = tid & 63;
  const int w    = tid >> 6;          // 0..3
  const int l31  = lane & 31;
  const int hi   = lane >> 5;         // 0..1
  const int bx   = blockIdx.x;        // 0..15
  const int by   = blockIdx.y;        // 0..31
  const int bh   = (bx & 7) + 8 * (by >> 3);   // XCD = bh&7
  const int x    = (bx >> 3) + 2 * (by & 7);   // 0..15

  const int wi = (bh < 16) ? w : (w ^ 1);
  const int qt = (wi == 0) ? 2 * x : (wi == 1) ? 63 - 2 * x
               : (wi == 2) ? 2 * x + 1 : 62 - 2 * x;
  const int q0w = qt * 32;
  const int NT  = (qt >> 1) + 1;      // 64-key tiles

  const __bf16* Qg = Q  + (size_t)bh * T * HD;
  const __bf16* Kg = K  + (size_t)bh * T * HD;
  const __bf16* Vg = Vt + (size_t)bh * HD * T;

  // Q B-fragments: col=q=l31; per k-step st: elements st*16 + hi*8 ..+8
  bf16x8 qfr[4];
  #pragma unroll
  for (int st = 0; st < 4; ++st)
    qfr[st] = *reinterpret_cast<const bf16x8*>(
        Qg + (size_t)(q0w + l31) * HD + st * 16 + hi * 8);

  f32x16 zv;
  #pragma unroll
  for (int i = 0; i < 16; ++i) zv[i] = 0.f;

  float m_run = -INFINITY, l_run = 0.f;
  f32x16 oacc0, oacc1;
  #pragma unroll
  for (int i = 0; i < 16; ++i) { oacc0[i] = 0.f; oacc1[i] = 0.f; }

  const __bf16* kbase = Kg + (size_t)l31 * HD + hi * 8;
  const __bf16* vbase = Vg + (size_t)l31 * T + hi * 8;

#define LOADK8(K0, K1, K2, K3, K4, K5, K6, K7, jj)                            \
  do {                                                                        \
    const __bf16* _kp = kbase + (size_t)(jj) * 64 * HD;                       \
    K0 = *reinterpret_cast<const bf16x8*>(_kp);                               \
    K1 = *reinterpret_cast<const bf16x8*>(_kp + 16);                          \
    K2 = *reinterpret_cast<const bf16x8*>(_kp + 32);                          \
    K3 = *reinterpret_cast<const bf16x8*>(_kp + 48);                          \
    const __bf16* _kq = _kp + (size_t)32 * HD;                                \
    K4 = *reinterpret_cast<const bf16x8*>(_kq);                               \
    K5 = *reinterpret_cast<const bf16x8*>(_kq + 16);                          \
    K6 = *reinterpret_cast<const bf16x8*>(_kq + 32);                          \
    K7 = *reinterpret_cast<const bf16x8*>(_kq + 48);                          \
  } while (0)

#define TILE64(K0, K1, K2, K3, K4, K5, K6, K7, jj)                            \
  do {                                                                        \
    /* V loads issued first; consumed after QK + softmax (~400 cy) */         \
    const __bf16* _vp = vbase + (size_t)(jj) * 64;                            \
    bf16x8 Va00 = *reinterpret_cast<const bf16x8*>(_vp);                      \
    bf16x8 Va01 = *reinterpret_cast<const bf16x8*>(_vp + 16);                 \
    bf16x8 Va10 = *reinterpret_cast<const bf16x8*>(_vp + (size_t)32 * T);     \
    bf16x8 Va11 = *reinterpret_cast<const bf16x8*>(_vp + (size_t)32 * T + 16);\
    bf16x8 Vb00 = *reinterpret_cast<const bf16x8*>(_vp + 32);                 \
    bf16x8 Vb01 = *reinterpret_cast<const bf16x8*>(_vp + 48);                 \
    bf16x8 Vb10 = *reinterpret_cast<const bf16x8*>(_vp + (size_t)32 * T + 32);\
    bf16x8 Vb11 = *reinterpret_cast<const bf16x8*>(_vp + (size_t)32 * T + 48);\
    /* QK: two halves, two 2-deep chains each, C-in = hoisted zv */           \
    f32x16 s0a = mfma32(K0, qfr[0], zv);                                      \
    f32x16 s0b = mfma32(K1, qfr[1], zv);                                      \
    f32x16 s1a = mfma32(K4, qfr[0], zv);                                      \
    f32x16 s1b = mfma32(K5, qfr[1], zv);                                      \
    s0a = mfma32(K2, qfr[2], s0a);                                            \
    s0b = mfma32(K3, qfr[3], s0b);                                            \
    s1a = mfma32(K6, qfr[2], s1a);                                            \
    s1b = mfma32(K7, qfr[3], s1b);                                            \
    f32x16 sv0, sv1;                                                          \
    _Pragma("unroll")                                                         \
    for (int _i = 0; _i < 16; ++_i) {                                         \
      sv0[_i] = s0a[_i] + s0b[_i];                                            \
      sv1[_i] = s1a[_i] + s1b[_i];                                            \
    }                                                                         \
    if ((jj) == NT - 1) { /* diagonal tile: causal mask both halves */        \
      const int _q  = q0w + l31;                                              \
      const int _k0 = (jj) * 64 + 4 * hi;                                     \
      _Pragma("unroll")                                                       \
      for (int _r = 0; _r < 16; ++_r) {                                       \
        const int _key = _k0 + (_r & 3) + 8 * (_r >> 2);                      \
        if (_key > _q)      sv0[_r] = -INFINITY;                              \
        if (_key + 32 > _q) sv1[_r] = -INFINITY;                              \
      }                                                                       \
    }                                                                         \
    /* one max tree over 32 values */                                         \
    float _mx[16];                                                            \
    _Pragma("unroll")                                                         \
    for (int _i = 0; _i < 16; ++_i) _mx[_i] = fmaxf(sv0[_i], sv1[_i]);        \
    _Pragma("unroll")                                                         \
    for (int _s = 8; _s > 0; _s >>= 1)                                        \
      _Pragma("unroll")                                                       \
      for (int _i = 0; _i < 8; ++_i)                                          \
        if (_i < _s) _mx[_i] = fmaxf(_mx[_i], _mx[_i + _s]);                  \
    union { float f; unsigned u; } _cv; _cv.f = _mx[0];                       \
    u32x2 _sw = plswap(_cv.u, _cv.u);                                         \
    union { unsigned u; float f; } _c0, _c1; _c0.u = _sw[0]; _c1.u = _sw[1];  \
    const float _pmax = fmaxf(_c0.f, _c1.f);                                  \
    if (__any(_pmax > m_run + 8.f)) {                                         \
      const float _mn = fmaxf(m_run, _pmax);                                  \
      const float _rs = exp2f(m_run - _mn);                                   \
      l_run *= _rs;                                                           \
      _Pragma("unroll")                                                       \
      for (int _i = 0; _i < 16; ++_i) { oacc0[_i] *= _rs; oacc1[_i] *= _rs; } \
      m_run = _mn;                                                            \
    }                                                                         \
    _Pragma("unroll")                                                         \
    for (int _i = 0; _i < 16; ++_i) {                                         \
      sv0[_i] = exp2f(sv0[_i] - m_run);                                       \
      sv1[_i] = exp2f(sv1[_i] - m_run);                                       \
    }                                                                         \
    float _sm[16];                                                            \
    _Pragma("unroll")                                                         \
    for (int _i = 0; _i < 16; ++_i) _sm[_i] = sv0[_i] + sv1[_i];              \
    _Pragma("unroll")                                                         \
    for (int _s = 8; _s > 0; _s >>= 1)                                        \
      _Pragma("unroll")                                                       \
      for (int _i = 0; _i < 8; ++_i)                                          \
        if (_i < _s) _sm[_i] += _sm[_i + _s];                                 \
    l_run += _sm[0];                                                          \
    unsigned _cp0[8], _cp1[8];                                                \
    _Pragma("unroll")                                                         \
    for (int _m = 0; _m < 4; ++_m) {                                          \
      _cp0[2 * _m]     = cvtpk(sv0[4 * _m],     sv0[4 * _m + 1]);             \
      _cp0[2 * _m + 1] = cvtpk(sv0[4 * _m + 2], sv0[4 * _m + 3]);             \
      _cp1[2 * _m]     = cvtpk(sv1[4 * _m],     sv1[4 * _m + 1]);             \
      _cp1[2 * _m + 1] = cvtpk(sv1[4 * _m + 2], sv1[4 * _m + 3]);             \
    }                                                                         \
    {                                                                         \
      u32x2 _r0 = plswap(_cp0[0], _cp0[2]);                                   \
      u32x2 _r1 = plswap(_cp0[1], _cp0[3]);                                   \
      union { u32x4 u; bf16x8 v; } _pu;                                       \
      _pu.u = (u32x4){_r0[0], _r1[0], _r0[1], _r1[1]};                        \
      oacc0 = mfma32(Va00, _pu.v, oacc0);                                     \
      oacc1 = mfma32(Va10, _pu.v, oacc1);                                     \
    }                                                                         \
    {                                                                         \
      u32x2 _r0 = plswap(_cp0[4], _cp0[6]);                                   \
      u32x2 _r1 = plswap(_cp0[5], _cp0[7]);                                   \
      union { u32x4 u; bf16x8 v; } _pu;                                       \
      _pu.u = (u32x4){_r0[0], _r1[0], _r0[1], _r1[1]};                        \
      oacc0 = mfma32(Va01, _pu.v, oacc0);                                     \
      oacc1 = mfma32(Va11, _pu.v, oacc1);                                     \
    }                                                                         \
    {                                                                         \
      u32x2 _r0 = plswap(_cp1[0], _cp1[2]);                                   \
      u32x2 _r1 = plswap(_cp1[1], _cp1[3]);                                   \
      union { u32x4 u; bf16x8 v; } _pu;                                       \
      _pu.u = (u32x4){_r0[0], _r1[0], _r0[1], _r1[1]};                        \
      oacc0 = mfma32(Vb00, _pu.v, oacc0);                                     \
      oacc1 = mfma32(Vb10, _pu.v, oacc1);                                     \
    }                                                                         \
    {                                                                         \
      u32x2 _r0 = plswap(_cp1[4], _cp1[6]);                                   \
      u32x2 _r1 = plswap(_cp1[5], _cp1[7]);                                   \
      union { u32x4 u; bf16x8 v; } _pu;                                       \
      _pu.u = (u32x4){_r0[0], _r1[0], _r0[1], _r1[1]};                        \
      oacc0 = mfma32(Vb01, _pu.v, oacc0);                                     \
      oacc1 = mfma32(Vb11, _pu.v, oacc1);                                     \
    }                                                                         \
  } while (0)

  bf16x8 kA0, kA1, kA2, kA3, kA4, kA5, kA6, kA7;
  bf16x8 kB0, kB1, kB2, kB3, kB4, kB5, kB6, kB7;

  LOADK8(kA0, kA1, kA2, kA3, kA4, kA5, kA6, kA7, 0);
  int j = 0;
  #pragma unroll 1
  for (;;) {
    if (j + 1 < NT) LOADK8(kB0, kB1, kB2, kB3, kB4, kB5, kB6, kB7, j + 1);
    TILE64(kA0, kA1, kA2, kA3, kA4, kA5, kA6, kA7, j);
    if (++j >= NT) break;
    if (j + 1 < NT) LOADK8(kA0, kA1, kA2, kA3, kA4, kA5, kA6, kA7, j + 1);
    TILE64(kB0, kB1, kB2, kB3, kB4, kB5, kB6, kB7, j);
    if (++j >= NT) break;
  }
#undef TILE64
#undef LOADK8

  // ---- epilogue: O rows hd = (reg&3)+8*(reg>>2)+4hi, q col = l31 ----
  const float l_tot = l_run + __shfl_xor(l_run, 32);
  const float inv = 1.f / l_tot;
  const int b = bh >> 4, h = bh & 15;
  const int q_abs = q0w + l31;
  const size_t rowbase = ((size_t)(b * T + q_abs)) * 1024 + h * 64;
  #pragma unroll
  for (int rg = 0; rg < 4; ++rg) {
    bf16x4 o0, o1;
    #pragma unroll
    for (int r = 0; r < 4; ++r) {
      o0[r] = (__bf16)(oacc0[rg * 4 + r] * inv);
      o1[r] = (__bf16)(oacc1[rg * 4 + r] * inv);
    }
    *reinterpret_cast<bf16x4*>(&Ob[rowbase + rg * 8 + hi * 4])      = o0;
    *reinterpret_cast<bf16x4*>(&Ob[rowbase + 32 + rg * 8 + hi * 4]) = o1;
  }
}

// ---------------------------------------------------------------------------
extern "C" void kernel_launch(void* const* d_in, const int* in_sizes, int n_in,
                              void* d_out, int out_size, void* d_ws, size_t ws_size,
                              hipStream_t stream) {
  const float* x    = (const float*)d_in[0];
  const float* cosT = (const float*)d_in[1];
  const float* sinT = (const float*)d_in[2];
  // d_in[3] = mask (causal, analytic)
  const float* wq   = (const float*)d_in[4];
  const float* wk   = (const float*)d_in[5];
  const float* wv   = (const float*)d_in[6];
  const float* wo   = (const float*)d_in[7];
  float* out = (float*)d_out;

  __bf16* xb   = (__bf16*)d_ws;
  __bf16* wqb  = xb  + XSZ;
  __bf16* wkb  = wqb + WSZ;
  __bf16* wvb  = wkb + WSZ;
  __bf16* wob  = wvb + WSZ;
  __bf16* Qh   = wob + WSZ;      // [bh][t][hd]  (pre-scaled by 0.125*log2e)
  __bf16* Kh   = Qh  + XSZ;      // [bh][t][hd]
  __bf16* Vth  = Kh  + XSZ;      // [bh][hd][t]
  __bf16* attb = Vth + XSZ;      // [M][1024]

  cvt_all<<<(XSZ + 4 * WSZ) / 8 / 256, 256, 0, stream>>>(x, wq, wk, wv, wo, xb);

  gemm_mfma<1><<<dim3(24, 32), 256, 0, stream>>>(
      xb, wqb, wkb, wvb, cosT, sinT, Qh, Kh, Vth);

  attn_v12<<<dim3(16, 32), 256, 0, stream>>>(Qh, Kh, Vth, attb);

  gemm_mfma<0><<<dim3(8, 32), 256, 0, stream>>>(
      attb, wob, nullptr, nullptr, nullptr, nullptr, out, nullptr, nullptr);
}

// Round 16
// 146.033 us; speedup vs baseline: 1.4034x; 1.0703x over previous
//
#include <hip/hip_runtime.h>
#include <math.h>

constexpr int D  = 1024;
constexpr int H  = 16;
constexpr int HD = 64;
constexpr int B  = 2;
constexpr int T  = 2048;
constexpr int M  = B * T;   // 4096

constexpr size_t XSZ = (size_t)M * D;   // 4,194,304
constexpr size_t WSZ = (size_t)D * D;   // 1,048,576

typedef float  f32x4   __attribute__((ext_vector_type(4)));
typedef float  f32x16  __attribute__((ext_vector_type(16)));
typedef __bf16 bf16x8  __attribute__((ext_vector_type(8)));
typedef __bf16 bf16x4  __attribute__((ext_vector_type(4)));
typedef unsigned u32x2 __attribute__((ext_vector_type(2)));
typedef unsigned u32x4 __attribute__((ext_vector_type(4)));

static __device__ inline f32x4 mfma16(bf16x8 a, bf16x8 b, f32x4 c) {
  return __builtin_amdgcn_mfma_f32_16x16x32_bf16(a, b, c, 0, 0, 0);
}
static __device__ inline f32x16 mfma32(bf16x8 a, bf16x8 b, f32x16 c) {
  return __builtin_amdgcn_mfma_f32_32x32x16_bf16(a, b, c, 0, 0, 0);
}
// pack two f32 -> u32 of 2 bf16 (lo = a, hi = b); no builtin on gfx950
static __device__ inline unsigned cvtpk(float a, float b) {
  unsigned r;
  asm("v_cvt_pk_bf16_f32 %0, %1, %2" : "=v"(r) : "v"(a), "v"(b));
  return r;
}
static __device__ inline u32x2 plswap(unsigned a, unsigned b) {
  return __builtin_amdgcn_permlane32_swap(a, b, false, false);
}
// async global->LDS, 16B per lane (dest = wave-uniform base + lane*16)
static __device__ inline void gload16(const __bf16* g, __bf16* l) {
  __builtin_amdgcn_global_load_lds(
      (const __attribute__((address_space(1))) void*)g,
      (__attribute__((address_space(3))) void*)l, 16, 0, 0);
}

// ---------------------------------------------------------------------------
// Fused fp32->bf16 convert of x + 4 weights into contiguous bf16 workspace.
// ---------------------------------------------------------------------------
__global__ __launch_bounds__(256)
void cvt_all(const float* __restrict__ x, const float* __restrict__ wq,
             const float* __restrict__ wk, const float* __restrict__ wv,
             const float* __restrict__ wo, __bf16* __restrict__ out) {
  size_t idx = ((size_t)blockIdx.x * 256 + threadIdx.x) * 8;
  const float* src;
  if      (idx < XSZ)            src = x  + idx;
  else if (idx < XSZ + WSZ)      src = wq + (idx - XSZ);
  else if (idx < XSZ + 2 * WSZ)  src = wk + (idx - XSZ - WSZ);
  else if (idx < XSZ + 3 * WSZ)  src = wv + (idx - XSZ - 2 * WSZ);
  else                           src = wo + (idx - XSZ - 3 * WSZ);
  float4 a = *reinterpret_cast<const float4*>(src);
  float4 b = *reinterpret_cast<const float4*>(src + 4);
  bf16x8 o;
  o[0] = (__bf16)a.x; o[1] = (__bf16)a.y; o[2] = (__bf16)a.z; o[3] = (__bf16)a.w;
  o[4] = (__bf16)b.x; o[5] = (__bf16)b.y; o[6] = (__bf16)b.z; o[7] = (__bf16)b.w;
  *reinterpret_cast<bf16x8*>(out + idx) = o;
}

// ---------------------------------------------------------------------------
// MFMA GEMM — m97 geometry: 128x128 tile, BK=64, 256 threads = 4 waves (2x2),
// per-wave 64x64, acc[4][4], 32 MFMA per K-iter, global_load_lds staging.
// MODE 1: fused QKV. Q/K: RoPE fused (Q pre-scaled by 0.125*log2e) and
//   written in attn MFMA-FRAGMENT order (see attn_v13 header). V written in
//   PV-fragment order. This makes every attn operand load a wave-uniform
//   base + lane*16 coalesced 1KB read (minimal L2 transactions).
// MODE 0: single GEMM (wo), fp32 out.
// ---------------------------------------------------------------------------
template<int MODE>
__global__ __launch_bounds__(256)
void gemm_mfma(const __bf16* __restrict__ A,
               const __bf16* __restrict__ W0, const __bf16* __restrict__ W1,
               const __bf16* __restrict__ W2,
               const float* __restrict__ cosT, const float* __restrict__ sinT,
               void* __restrict__ out0, void* __restrict__ out1,
               void* __restrict__ out2) {
  __shared__ __bf16 As[128 * 64];
  __shared__ __bf16 Bs[128 * 64];

  const int tid  = threadIdx.x;
  const int lane = tid & 63;
  const int w    = tid >> 6;     // 0..3
  const int wm   = w >> 1;       // 0..1 (64 rows each)
  const int wn   = w & 1;        // 0..1 (64 cols each)
  const int l15  = lane & 15, lg = lane >> 4;
  const int m0   = blockIdx.y * 128;

  int which, n0;
  const __bf16* Bw;
  if (MODE == 1) {
    which = blockIdx.x >> 3;
    n0 = (blockIdx.x & 7) * 128;
    Bw = which == 0 ? W0 : which == 1 ? W1 : W2;
  } else {
    which = 0;
    n0 = blockIdx.x * 128;
    Bw = W0;
  }

  f32x4 acc[4][4];
  #pragma unroll
  for (int i = 0; i < 4; ++i)
    #pragma unroll
    for (int j = 0; j < 4; ++j) acc[i][j] = (f32x4){0.f, 0.f, 0.f, 0.f};

  const int r0 = tid >> 3;          // 0..31
  const int c0 = (tid & 7) * 8;     // 0..56

  for (int k0 = 0; k0 < 1024; k0 += 64) {
    #pragma unroll
    for (int i = 0; i < 4; ++i) {
      gload16(A  + (size_t)(m0 + r0 + 32 * i) * 1024 + k0 + c0,
              As + (tid + 256 * i) * 8);
      gload16(Bw + (size_t)(n0 + r0 + 32 * i) * 1024 + k0 + c0,
              Bs + (tid + 256 * i) * 8);
    }
    __syncthreads();   // drains vmcnt -> LDS tiles ready

    #pragma unroll
    for (int ks = 0; ks < 2; ++ks) {
      bf16x8 af[4], bfr[4];
      #pragma unroll
      for (int mt = 0; mt < 4; ++mt)
        af[mt] = *reinterpret_cast<const bf16x8*>(
            &As[(wm * 64 + mt * 16 + l15) * 64 + ks * 32 + lg * 8]);
      #pragma unroll
      for (int nt = 0; nt < 4; ++nt)
        bfr[nt] = *reinterpret_cast<const bf16x8*>(
            &Bs[(wn * 64 + nt * 16 + l15) * 64 + ks * 32 + lg * 8]);
      #pragma unroll
      for (int mt = 0; mt < 4; ++mt)
        #pragma unroll
        for (int nt = 0; nt < 4; ++nt)
          acc[mt][nt] = mfma16(af[mt], bfr[nt], acc[mt][nt]);
    }
    __syncthreads();
  }

  // Frag: n = n0 + wn*64 + nt*16 + l15 ; m = m0 + wm*64 + mt*16 + lg*4 + r
  if (MODE == 0) {
    float* o = (float*)out0;
    #pragma unroll
    for (int mt = 0; mt < 4; ++mt) {
      const int mb = m0 + wm * 64 + mt * 16 + lg * 4;
      #pragma unroll
      for (int nt = 0; nt < 4; ++nt) {
        const int n = n0 + wn * 64 + nt * 16 + l15;
        #pragma unroll
        for (int r = 0; r < 4; ++r)
          o[(size_t)(mb + r) * 1024 + n] = acc[mt][nt][r];
      }
    }
  } else if (which < 2) {
    // Q or K: RoPE fused; Q scaled by 0.125*log2(e). Fragment-order store:
    //   element (t, hd):  L = (t&31) | (l15>>3)<<5 , e = hd&7 = l15&7
    //   Q: [bh][t>>5][st][L][e]            (st = nt for hd, nt+2 for hd+32)
    //   K: [bh][t>>6][(t>>5)&1][st][L][e]
    __bf16* dst = which == 0 ? (__bf16*)out0 : (__bf16*)out1;
    const float qs = (which == 0) ? 0.180336880f : 1.0f;
    const int h = (n0 + wn * 64) >> 6;
    const int e  = l15 & 7;
    const int Lh = (l15 >> 3) << 5;
    #pragma unroll
    for (int mt = 0; mt < 4; ++mt) {
      const int tb   = m0 + wm * 64 + mt * 16 + lg * 4;
      const int bb   = tb >> 11;
      const int tloc = tb & 2047;
      const int bh   = bb * H + h;
      #pragma unroll
      for (int r = 0; r < 4; ++r) {
        const int t = tloc + r;
        const int L = (t & 31) + Lh;
        size_t fb;
        if (MODE == 1 && which == 0)
          fb = ((size_t)bh * 64 + (t >> 5)) * 4;
        else
          fb = (((size_t)bh * 32 + (t >> 6)) * 2 + ((t >> 5) & 1)) * 4;
        #pragma unroll
        for (int nt = 0; nt < 2; ++nt) {
          const int hd = nt * 16 + l15;
          const float c = cosT[t * HD + hd];
          const float s = sinT[t * HD + hd];
          const float v1 = acc[mt][nt][r];
          const float v2 = acc[mt][nt + 2][r];
          dst[(fb + nt)     * 512 + L * 8 + e] = (__bf16)((v1 * c - v2 * s) * qs);
          dst[(fb + nt + 2) * 512 + L * 8 + e] = (__bf16)((v2 * c + v1 * s) * qs);
        }
      }
    }
  } else {
    // V: PV-fragment order [bh][t>>6][dg=hd>>5][kc=(t&63)>>4][L][e]
    //   L = (hd&31) | ((t>>3)&1)<<5 , e = t&7 (bf16x4 over r, 4-aligned)
    __bf16* dst = (__bf16*)out2;
    const int h = (n0 + wn * 64) >> 6;
    #pragma unroll
    for (int mt = 0; mt < 4; ++mt) {
      const int tb   = m0 + wm * 64 + mt * 16 + lg * 4;
      const int bb   = tb >> 11;
      const int tloc = tb & 2047;
      const int bh   = bb * H + h;
      const int jt   = tloc >> 6;
      const int kt   = tloc & 63;          // mt*16 + lg*4
      const int Lk   = ((kt >> 3) & 1) << 5;
      const int e0   = kt & 7;             // (lg&1)*4, 4-aligned
      const size_t fb = (((size_t)bh * 32 + jt) * 2) * 4 + (kt >> 4);
      #pragma unroll
      for (int nt = 0; nt < 4; ++nt) {
        const int hd = nt * 16 + l15;
        const int dg = hd >> 5;
        const int L  = (hd & 31) + Lk;
        bf16x4 ov;
        #pragma unroll
        for (int r = 0; r < 4; ++r) ov[r] = (__bf16)acc[mt][nt][r];
        *reinterpret_cast<bf16x4*>(
            &dst[(fb + (size_t)dg * 4) * 512 + L * 8 + e0]) = ov;
      }
    }
  }
}

// ---------------------------------------------------------------------------
// attn_v13: v12 structure (64-key tiles, one softmax pass, defer-max, no
// barriers, no LDS) with Q/K/V read from FRAGMENT-ORDER buffers:
// every operand load = wave-uniform base + lane*16 -> coalesced 1KB, 4 cache
// lines (v12's per-lane row loads touched 32 lines per instruction -> 8x L2
// transaction amplification, the hypothesized 60% stall).
//   Qf: [bh][qt][st][lane][8]      (4 frags / 32-q tile)
//   Kf: [bh][jt][g][st][lane][8]   (8 frags / 64-key tile)
//   Vf: [bh][jt][dg][kc][lane][8]  (8 frags / 64-key tile)
// Per-SIMD balance: wave pairs {2x,63-2x}: 33 tiles. XCD = bh&7.
// ---------------------------------------------------------------------------
__global__ __launch_bounds__(256, 2)
void attn_v13(const __bf16* __restrict__ Qf, const __bf16* __restrict__ Kf,
              const __bf16* __restrict__ Vf, __bf16* __restrict__ Ob) {
  const int tid  = threadIdx.x;
  const int lane = tid & 63;
  const int w    = tid >> 6;          // 0..3
  const int l31  = lane & 31;
  const int hi   = lane >> 5;         // 0..1
  const int bx   = blockIdx.x;        // 0..15
  const int by   = blockIdx.y;        // 0..31
  const int bh   = (bx & 7) + 8 * (by >> 3);   // XCD = bh&7
  const int x    = (bx >> 3) + 2 * (by & 7);   // 0..15

  const int wi = (bh < 16) ? w : (w ^ 1);
  const int qt = (wi == 0) ? 2 * x : (wi == 1) ? 63 - 2 * x
               : (wi == 2) ? 2 * x + 1 : 62 - 2 * x;
  const int q0w = qt * 32;
  const int NT  = (qt >> 1) + 1;      // 64-key tiles

  // Q fragments: 4 coalesced loads
  const __bf16* qbase = Qf + (((size_t)bh * 64 + qt) * 4) * 512 + lane * 8;
  bf16x8 qfr[4];
  #pragma unroll
  for (int st = 0; st < 4; ++st)
    qfr[st] = *reinterpret_cast<const bf16x8*>(qbase + st * 512);

  f32x16 zv;
  #pragma unroll
  for (int i = 0; i < 16; ++i) zv[i] = 0.f;

  float m_run = -INFINITY, l_run = 0.f;
  f32x16 oacc0, oacc1;
  #pragma unroll
  for (int i = 0; i < 16; ++i) { oacc0[i] = 0.f; oacc1[i] = 0.f; }

  const __bf16* kbase = Kf + ((size_t)bh * 32 * 8) * 512 + lane * 8;
  const __bf16* vbase = Vf + ((size_t)bh * 32 * 8) * 512 + lane * 8;

#define LOADK8(K0, K1, K2, K3, K4, K5, K6, K7, jj)                            \
  do {                                                                        \
    const __bf16* _kp = kbase + (size_t)(jj) * 8 * 512;                       \
    K0 = *reinterpret_cast<const bf16x8*>(_kp);                               \
    K1 = *reinterpret_cast<const bf16x8*>(_kp + 512);                         \
    K2 = *reinterpret_cast<const bf16x8*>(_kp + 1024);                        \
    K3 = *reinterpret_cast<const bf16x8*>(_kp + 1536);                        \
    K4 = *reinterpret_cast<const bf16x8*>(_kp + 2048);                        \
    K5 = *reinterpret_cast<const bf16x8*>(_kp + 2560);                        \
    K6 = *reinterpret_cast<const bf16x8*>(_kp + 3072);                        \
    K7 = *reinterpret_cast<const bf16x8*>(_kp + 3584);                        \
  } while (0)

#define TILE64(K0, K1, K2, K3, K4, K5, K6, K7, jj)                            \
  do {                                                                        \
    /* V loads issued first; consumed after QK + softmax (~400 cy) */         \
    const __bf16* _vp = vbase + (size_t)(jj) * 8 * 512;                       \
    bf16x8 Va00 = *reinterpret_cast<const bf16x8*>(_vp);                      \
    bf16x8 Va01 = *reinterpret_cast<const bf16x8*>(_vp + 512);                \
    bf16x8 Vb00 = *reinterpret_cast<const bf16x8*>(_vp + 1024);               \
    bf16x8 Vb01 = *reinterpret_cast<const bf16x8*>(_vp + 1536);               \
    bf16x8 Va10 = *reinterpret_cast<const bf16x8*>(_vp + 2048);               \
    bf16x8 Va11 = *reinterpret_cast<const bf16x8*>(_vp + 2560);               \
    bf16x8 Vb10 = *reinterpret_cast<const bf16x8*>(_vp + 3072);               \
    bf16x8 Vb11 = *reinterpret_cast<const bf16x8*>(_vp + 3584);               \
    /* QK: two halves, two 2-deep chains each, C-in = hoisted zv */           \
    f32x16 s0a = mfma32(K0, qfr[0], zv);                                      \
    f32x16 s0b = mfma32(K1, qfr[1], zv);                                      \
    f32x16 s1a = mfma32(K4, qfr[0], zv);                                      \
    f32x16 s1b = mfma32(K5, qfr[1], zv);                                      \
    s0a = mfma32(K2, qfr[2], s0a);                                            \
    s0b = mfma32(K3, qfr[3], s0b);                                            \
    s1a = mfma32(K6, qfr[2], s1a);                                            \
    s1b = mfma32(K7, qfr[3], s1b);                                            \
    f32x16 sv0, sv1;                                                          \
    _Pragma("unroll")                                                         \
    for (int _i = 0; _i < 16; ++_i) {                                         \
      sv0[_i] = s0a[_i] + s0b[_i];                                            \
      sv1[_i] = s1a[_i] + s1b[_i];                                            \
    }                                                                         \
    if ((jj) == NT - 1) { /* diagonal tile: causal mask both halves */        \
      const int _q  = q0w + l31;                                              \
      const int _k0 = (jj) * 64 + 4 * hi;                                     \
      _Pragma("unroll")                                                       \
      for (int _r = 0; _r < 16; ++_r) {                                       \
        const int _key = _k0 + (_r & 3) + 8 * (_r >> 2);                      \
        if (_key > _q)      sv0[_r] = -INFINITY;                              \
        if (_key + 32 > _q) sv1[_r] = -INFINITY;                              \
      }                                                                       \
    }                                                                         \
    /* one max tree over 32 values */                                         \
    float _mx[16];                                                            \
    _Pragma("unroll")                                                         \
    for (int _i = 0; _i < 16; ++_i) _mx[_i] = fmaxf(sv0[_i], sv1[_i]);        \
    _Pragma("unroll")                                                         \
    for (int _s = 8; _s > 0; _s >>= 1)                                        \
      _Pragma("unroll")                                                       \
      for (int _i = 0; _i < 8; ++_i)                                          \
        if (_i < _s) _mx[_i] = fmaxf(_mx[_i], _mx[_i + _s]);                  \
    union { float f; unsigned u; } _cv; _cv.f = _mx[0];                       \
    u32x2 _sw = plswap(_cv.u, _cv.u);                                         \
    union { unsigned u; float f; } _c0, _c1; _c0.u = _sw[0]; _c1.u = _sw[1];  \
    const float _pmax = fmaxf(_c0.f, _c1.f);                                  \
    if (__any(_pmax > m_run + 8.f)) {                                         \
      const float _mn = fmaxf(m_run, _pmax);                                  \
      const float _rs = exp2f(m_run - _mn);                                   \
      l_run *= _rs;                                                           \
      _Pragma("unroll")                                                       \
      for (int _i = 0; _i < 16; ++_i) { oacc0[_i] *= _rs; oacc1[_i] *= _rs; } \
      m_run = _mn;                                                            \
    }                                                                         \
    _Pragma("unroll")                                                         \
    for (int _i = 0; _i < 16; ++_i) {                                         \
      sv0[_i] = exp2f(sv0[_i] - m_run);                                       \
      sv1[_i] = exp2f(sv1[_i] - m_run);                                       \
    }                                                                         \
    float _sm[16];                                                            \
    _Pragma("unroll")                                                         \
    for (int _i = 0; _i < 16; ++_i) _sm[_i] = sv0[_i] + sv1[_i];              \
    _Pragma("unroll")                                                         \
    for (int _s = 8; _s > 0; _s >>= 1)                                        \
      _Pragma("unroll")                                                       \
      for (int _i = 0; _i < 8; ++_i)                                          \
        if (_i < _s) _sm[_i] += _sm[_i + _s];                                 \
    l_run += _sm[0];                                                          \
    unsigned _cp0[8], _cp1[8];                                                \
    _Pragma("unroll")                                                         \
    for (int _m = 0; _m < 4; ++_m) {                                          \
      _cp0[2 * _m]     = cvtpk(sv0[4 * _m],     sv0[4 * _m + 1]);             \
      _cp0[2 * _m + 1] = cvtpk(sv0[4 * _m + 2], sv0[4 * _m + 3]);             \
      _cp1[2 * _m]     = cvtpk(sv1[4 * _m],     sv1[4 * _m + 1]);             \
      _cp1[2 * _m + 1] = cvtpk(sv1[4 * _m + 2], sv1[4 * _m + 3]);             \
    }                                                                         \
    {                                                                         \
      u32x2 _r0 = plswap(_cp0[0], _cp0[2]);                                   \
      u32x2 _r1 = plswap(_cp0[1], _cp0[3]);                                   \
      union { u32x4 u; bf16x8 v; } _pu;                                       \
      _pu.u = (u32x4){_r0[0], _r1[0], _r0[1], _r1[1]};                        \
      oacc0 = mfma32(Va00, _pu.v, oacc0);                                     \
      oacc1 = mfma32(Va10, _pu.v, oacc1);                                     \
    }                                                                         \
    {                                                                         \
      u32x2 _r0 = plswap(_cp0[4], _cp0[6]);                                   \
      u32x2 _r1 = plswap(_cp0[5], _cp0[7]);                                   \
      union { u32x4 u; bf16x8 v; } _pu;                                       \
      _pu.u = (u32x4){_r0[0], _r1[0], _r0[1], _r1[1]};                        \
      oacc0 = mfma32(Va01, _pu.v, oacc0);                                     \
      oacc1 = mfma32(Va11, _pu.v, oacc1);                                     \
    }                                                                         \
    {                                                                         \
      u32x2 _r0 = plswap(_cp1[0], _cp1[2]);                                   \
      u32x2 _r1 = plswap(_cp1[1], _cp1[3]);                                   \
      union { u32x4 u; bf16x8 v; } _pu;                                       \
      _pu.u = (u32x4){_r0[0], _r1[0], _r0[1], _r1[1]};                        \
      oacc0 = mfma32(Vb00, _pu.v, oacc0);                                     \
      oacc1 = mfma32(Vb10, _pu.v, oacc1);                                     \
    }                                                                         \
    {                                                                         \
      u32x2 _r0 = plswap(_cp1[4], _cp1[6]);                                   \
      u32x2 _r1 = plswap(_cp1[5], _cp1[7]);                                   \
      union { u32x4 u; bf16x8 v; } _pu;                                       \
      _pu.u = (u32x4){_r0[0], _r1[0], _r0[1], _r1[1]};                        \
      oacc0 = mfma32(Vb01, _pu.v, oacc0);                                     \
      oacc1 = mfma32(Vb11, _pu.v, oacc1);                                     \
    }                                                                         \
  } while (0)

  bf16x8 kA0, kA1, kA2, kA3, kA4, kA5, kA6, kA7;
  bf16x8 kB0, kB1, kB2, kB3, kB4, kB5, kB6, kB7;

  LOADK8(kA0, kA1, kA2, kA3, kA4, kA5, kA6, kA7, 0);
  int j = 0;
  #pragma unroll 1
  for (;;) {
    if (j + 1 < NT) LOADK8(kB0, kB1, kB2, kB3, kB4, kB5, kB6, kB7, j + 1);
    TILE64(kA0, kA1, kA2, kA3, kA4, kA5, kA6, kA7, j);
    if (++j >= NT) break;
    if (j + 1 < NT) LOADK8(kA0, kA1, kA2, kA3, kA4, kA5, kA6, kA7, j + 1);
    TILE64(kB0, kB1, kB2, kB3, kB4, kB5, kB6, kB7, j);
    if (++j >= NT) break;
  }
#undef TILE64
#undef LOADK8

  // ---- epilogue: O rows hd = (reg&3)+8*(reg>>2)+4hi, q col = l31 ----
  const float l_tot = l_run + __shfl_xor(l_run, 32);
  const float inv = 1.f / l_tot;
  const int b = bh >> 4, h = bh & 15;
  const int q_abs = q0w + l31;
  const size_t rowbase = ((size_t)(b * T + q_abs)) * 1024 + h * 64;
  #pragma unroll
  for (int rg = 0; rg < 4; ++rg) {
    bf16x4 o0, o1;
    #pragma unroll
    for (int r = 0; r < 4; ++r) {
      o0[r] = (__bf16)(oacc0[rg * 4 + r] * inv);
      o1[r] = (__bf16)(oacc1[rg * 4 + r] * inv);
    }
    *reinterpret_cast<bf16x4*>(&Ob[rowbase + rg * 8 + hi * 4])      = o0;
    *reinterpret_cast<bf16x4*>(&Ob[rowbase + 32 + rg * 8 + hi * 4]) = o1;
  }
}

// ---------------------------------------------------------------------------
extern "C" void kernel_launch(void* const* d_in, const int* in_sizes, int n_in,
                              void* d_out, int out_size, void* d_ws, size_t ws_size,
                              hipStream_t stream) {
  const float* x    = (const float*)d_in[0];
  const float* cosT = (const float*)d_in[1];
  const float* sinT = (const float*)d_in[2];
  // d_in[3] = mask (causal, analytic)
  const float* wq   = (const float*)d_in[4];
  const float* wk   = (const float*)d_in[5];
  const float* wv   = (const float*)d_in[6];
  const float* wo   = (const float*)d_in[7];
  float* out = (float*)d_out;

  __bf16* xb   = (__bf16*)d_ws;
  __bf16* wqb  = xb  + XSZ;
  __bf16* wkb  = wqb + WSZ;
  __bf16* wvb  = wkb + WSZ;
  __bf16* wob  = wvb + WSZ;
  __bf16* Qfb  = wob + WSZ;      // fragment-order Q (pre-scaled)
  __bf16* Kfb  = Qfb + XSZ;      // fragment-order K
  __bf16* Vfb  = Kfb + XSZ;      // fragment-order V
  __bf16* attb = Vfb + XSZ;      // [M][1024]

  cvt_all<<<(XSZ + 4 * WSZ) / 8 / 256, 256, 0, stream>>>(x, wq, wk, wv, wo, xb);

  gemm_mfma<1><<<dim3(24, 32), 256, 0, stream>>>(
      xb, wqb, wkb, wvb, cosT, sinT, Qfb, Kfb, Vfb);

  attn_v13<<<dim3(16, 32), 256, 0, stream>>>(Qfb, Kfb, Vfb, attb);

  gemm_mfma<0><<<dim3(8, 32), 256, 0, stream>>>(
      attb, wob, nullptr, nullptr, nullptr, nullptr, out, nullptr, nullptr);
}

// Round 17
// 143.518 us; speedup vs baseline: 1.4280x; 1.0175x over previous
//
#include <hip/hip_runtime.h>
#include <math.h>

constexpr int D  = 1024;
constexpr int H  = 16;
constexpr int HD = 64;
constexpr int B  = 2;
constexpr int T  = 2048;
constexpr int M  = B * T;   // 4096

constexpr size_t XSZ = (size_t)M * D;   // 4,194,304
constexpr size_t WSZ = (size_t)D * D;   // 1,048,576

typedef float  f32x4   __attribute__((ext_vector_type(4)));
typedef float  f32x16  __attribute__((ext_vector_type(16)));
typedef __bf16 bf16x8  __attribute__((ext_vector_type(8)));
typedef __bf16 bf16x4  __attribute__((ext_vector_type(4)));
typedef unsigned u32x2 __attribute__((ext_vector_type(2)));
typedef unsigned u32x4 __attribute__((ext_vector_type(4)));

static __device__ inline f32x4 mfma16(bf16x8 a, bf16x8 b, f32x4 c) {
  return __builtin_amdgcn_mfma_f32_16x16x32_bf16(a, b, c, 0, 0, 0);
}
static __device__ inline f32x16 mfma32(bf16x8 a, bf16x8 b, f32x16 c) {
  return __builtin_amdgcn_mfma_f32_32x32x16_bf16(a, b, c, 0, 0, 0);
}
// pack two f32 -> u32 of 2 bf16 (lo = a, hi = b); no builtin on gfx950
static __device__ inline unsigned cvtpk(float a, float b) {
  unsigned r;
  asm("v_cvt_pk_bf16_f32 %0, %1, %2" : "=v"(r) : "v"(a), "v"(b));
  return r;
}
static __device__ inline u32x2 plswap(unsigned a, unsigned b) {
  return __builtin_amdgcn_permlane32_swap(a, b, false, false);
}
// async global->LDS, 16B per lane (dest = wave-uniform base + lane*16)
static __device__ inline void gload16(const __bf16* g, __bf16* l) {
  __builtin_amdgcn_global_load_lds(
      (const __attribute__((address_space(1))) void*)g,
      (__attribute__((address_space(3))) void*)l, 16, 0, 0);
}

// ---------------------------------------------------------------------------
// Fused fp32->bf16 convert of x + 4 weights into contiguous bf16 workspace.
// ---------------------------------------------------------------------------
__global__ __launch_bounds__(256)
void cvt_all(const float* __restrict__ x, const float* __restrict__ wq,
             const float* __restrict__ wk, const float* __restrict__ wv,
             const float* __restrict__ wo, __bf16* __restrict__ out) {
  size_t idx = ((size_t)blockIdx.x * 256 + threadIdx.x) * 8;
  const float* src;
  if      (idx < XSZ)            src = x  + idx;
  else if (idx < XSZ + WSZ)      src = wq + (idx - XSZ);
  else if (idx < XSZ + 2 * WSZ)  src = wk + (idx - XSZ - WSZ);
  else if (idx < XSZ + 3 * WSZ)  src = wv + (idx - XSZ - 2 * WSZ);
  else                           src = wo + (idx - XSZ - 3 * WSZ);
  float4 a = *reinterpret_cast<const float4*>(src);
  float4 b = *reinterpret_cast<const float4*>(src + 4);
  bf16x8 o;
  o[0] = (__bf16)a.x; o[1] = (__bf16)a.y; o[2] = (__bf16)a.z; o[3] = (__bf16)a.w;
  o[4] = (__bf16)b.x; o[5] = (__bf16)b.y; o[6] = (__bf16)b.z; o[7] = (__bf16)b.w;
  *reinterpret_cast<bf16x8*>(out + idx) = o;
}

// ---------------------------------------------------------------------------
// MFMA GEMM. MODE 1: 128x128 tile, fused QKV -> fragment-order Q/K/V.
// MODE 0: 64x128 tile (grid (8,64)=512 blocks = 2/CU; the 128x128 version
// capped WO at 256 blocks = 1 block/CU, half the machine idle), fp32 out.
// Both: BK=64, 256 thr = 4 waves (2x2), global_load_lds staging.
// ---------------------------------------------------------------------------
template<int MODE>
__global__ __launch_bounds__(256)
void gemm_mfma(const __bf16* __restrict__ A,
               const __bf16* __restrict__ W0, const __bf16* __restrict__ W1,
               const __bf16* __restrict__ W2,
               const float* __restrict__ cosT, const float* __restrict__ sinT,
               void* __restrict__ out0, void* __restrict__ out1,
               void* __restrict__ out2) {
  constexpr int BM  = (MODE == 0) ? 64 : 128;   // rows per block
  constexpr int NMT = BM / 32;                  // per-wave m-frags (2 or 4)
  __shared__ __bf16 As[BM * 64];
  __shared__ __bf16 Bs[128 * 64];

  const int tid  = threadIdx.x;
  const int lane = tid & 63;
  const int w    = tid >> 6;     // 0..3
  const int wm   = w >> 1;       // 0..1
  const int wn   = w & 1;        // 0..1 (64 cols each)
  const int l15  = lane & 15, lg = lane >> 4;
  const int m0   = blockIdx.y * BM;

  int which, n0;
  const __bf16* Bw;
  if (MODE == 1) {
    which = blockIdx.x >> 3;
    n0 = (blockIdx.x & 7) * 128;
    Bw = which == 0 ? W0 : which == 1 ? W1 : W2;
  } else {
    which = 0;
    n0 = blockIdx.x * 128;
    Bw = W0;
  }

  f32x4 acc[NMT][4];
  #pragma unroll
  for (int i = 0; i < NMT; ++i)
    #pragma unroll
    for (int j = 0; j < 4; ++j) acc[i][j] = (f32x4){0.f, 0.f, 0.f, 0.f};

  const int r0 = tid >> 3;          // 0..31
  const int c0 = (tid & 7) * 8;     // 0..56

  for (int k0 = 0; k0 < 1024; k0 += 64) {
    #pragma unroll
    for (int i = 0; i < BM / 32; ++i)
      gload16(A + (size_t)(m0 + r0 + 32 * i) * 1024 + k0 + c0,
              As + (tid + 256 * i) * 8);
    #pragma unroll
    for (int i = 0; i < 4; ++i)
      gload16(Bw + (size_t)(n0 + r0 + 32 * i) * 1024 + k0 + c0,
              Bs + (tid + 256 * i) * 8);
    __syncthreads();   // drains vmcnt -> LDS tiles ready

    #pragma unroll
    for (int ks = 0; ks < 2; ++ks) {
      bf16x8 af[NMT], bfr[4];
      #pragma unroll
      for (int mt = 0; mt < NMT; ++mt)
        af[mt] = *reinterpret_cast<const bf16x8*>(
            &As[(wm * (BM / 2) + mt * 16 + l15) * 64 + ks * 32 + lg * 8]);
      #pragma unroll
      for (int nt = 0; nt < 4; ++nt)
        bfr[nt] = *reinterpret_cast<const bf16x8*>(
            &Bs[(wn * 64 + nt * 16 + l15) * 64 + ks * 32 + lg * 8]);
      #pragma unroll
      for (int mt = 0; mt < NMT; ++mt)
        #pragma unroll
        for (int nt = 0; nt < 4; ++nt)
          acc[mt][nt] = mfma16(af[mt], bfr[nt], acc[mt][nt]);
    }
    __syncthreads();
  }

  // Frag: n = n0 + wn*64 + nt*16 + l15 ; m = m0 + wm*(BM/2) + mt*16 + lg*4 + r
  if (MODE == 0) {
    float* o = (float*)out0;
    #pragma unroll
    for (int mt = 0; mt < NMT; ++mt) {
      const int mb = m0 + wm * (BM / 2) + mt * 16 + lg * 4;
      #pragma unroll
      for (int nt = 0; nt < 4; ++nt) {
        const int n = n0 + wn * 64 + nt * 16 + l15;
        #pragma unroll
        for (int r = 0; r < 4; ++r)
          o[(size_t)(mb + r) * 1024 + n] = acc[mt][nt][r];
      }
    }
  } else if (which < 2) {
    // Q or K: RoPE fused; Q scaled by 0.125*log2(e). Fragment-order store:
    //   element (t, hd):  L = (t&31) | (l15>>3)<<5 , e = hd&7 = l15&7
    //   Q: [bh][t>>5][st][L][e]
    //   K: [bh][t>>6][(t>>5)&1][st][L][e]
    __bf16* dst = which == 0 ? (__bf16*)out0 : (__bf16*)out1;
    const float qs = (which == 0) ? 0.180336880f : 1.0f;
    const int h = (n0 + wn * 64) >> 6;
    const int e  = l15 & 7;
    const int Lh = (l15 >> 3) << 5;
    #pragma unroll
    for (int mt = 0; mt < NMT; ++mt) {
      const int tb   = m0 + wm * (BM / 2) + mt * 16 + lg * 4;
      const int bb   = tb >> 11;
      const int tloc = tb & 2047;
      const int bh   = bb * H + h;
      #pragma unroll
      for (int r = 0; r < 4; ++r) {
        const int t = tloc + r;
        const int L = (t & 31) + Lh;
        size_t fb;
        if (which == 0)
          fb = ((size_t)bh * 64 + (t >> 5)) * 4;
        else
          fb = (((size_t)bh * 32 + (t >> 6)) * 2 + ((t >> 5) & 1)) * 4;
        #pragma unroll
        for (int nt = 0; nt < 2; ++nt) {
          const int hd = nt * 16 + l15;
          const float c = cosT[t * HD + hd];
          const float s = sinT[t * HD + hd];
          const float v1 = acc[mt][nt][r];
          const float v2 = acc[mt][nt + 2][r];
          dst[(fb + nt)     * 512 + L * 8 + e] = (__bf16)((v1 * c - v2 * s) * qs);
          dst[(fb + nt + 2) * 512 + L * 8 + e] = (__bf16)((v2 * c + v1 * s) * qs);
        }
      }
    }
  } else {
    // V: PV-fragment order [bh][t>>6][dg=hd>>5][kc=(t&63)>>4][L][e]
    __bf16* dst = (__bf16*)out2;
    const int h = (n0 + wn * 64) >> 6;
    #pragma unroll
    for (int mt = 0; mt < NMT; ++mt) {
      const int tb   = m0 + wm * (BM / 2) + mt * 16 + lg * 4;
      const int bb   = tb >> 11;
      const int tloc = tb & 2047;
      const int bh   = bb * H + h;
      const int jt   = tloc >> 6;
      const int kt   = tloc & 63;
      const int Lk   = ((kt >> 3) & 1) << 5;
      const int e0   = kt & 7;
      const size_t fb = (((size_t)bh * 32 + jt) * 2) * 4 + (kt >> 4);
      #pragma unroll
      for (int nt = 0; nt < 4; ++nt) {
        const int hd = nt * 16 + l15;
        const int dg = hd >> 5;
        const int L  = (hd & 31) + Lk;
        bf16x4 ov;
        #pragma unroll
        for (int r = 0; r < 4; ++r) ov[r] = (__bf16)acc[mt][nt][r];
        *reinterpret_cast<bf16x4*>(
            &dst[(fb + (size_t)dg * 4) * 512 + L * 8 + e0]) = ov;
      }
    }
  }
}

// ---------------------------------------------------------------------------
// attn_v14: v13 + sched_barrier(0) pins after each load group.
// v13's VGPR=112 proved the compiler SANK the K-prefetch and V loads to
// their uses (the register pipeline needs ~180 live VGPRs), exposing full
// L2 latency per tile. sched_barrier(0) after each load block forbids the
// scheduler from moving loads past it -> K(j+1) and V(j) issue a full
// compute-phase ahead. Everything else identical to v13.
// ---------------------------------------------------------------------------
__global__ __launch_bounds__(256, 2)
void attn_v14(const __bf16* __restrict__ Qf, const __bf16* __restrict__ Kf,
              const __bf16* __restrict__ Vf, __bf16* __restrict__ Ob) {
  const int tid  = threadIdx.x;
  const int lane = tid & 63;
  const int w    = tid >> 6;          // 0..3
  const int l31  = lane & 31;
  const int hi   = lane >> 5;         // 0..1
  const int bx   = blockIdx.x;        // 0..15
  const int by   = blockIdx.y;        // 0..31
  const int bh   = (bx & 7) + 8 * (by >> 3);   // XCD = bh&7
  const int x    = (bx >> 3) + 2 * (by & 7);   // 0..15

  const int wi = (bh < 16) ? w : (w ^ 1);
  const int qt = (wi == 0) ? 2 * x : (wi == 1) ? 63 - 2 * x
               : (wi == 2) ? 2 * x + 1 : 62 - 2 * x;
  const int q0w = qt * 32;
  const int NT  = (qt >> 1) + 1;      // 64-key tiles

  // Q fragments: 4 coalesced loads
  const __bf16* qbase = Qf + (((size_t)bh * 64 + qt) * 4) * 512 + lane * 8;
  bf16x8 qfr[4];
  #pragma unroll
  for (int st = 0; st < 4; ++st)
    qfr[st] = *reinterpret_cast<const bf16x8*>(qbase + st * 512);

  f32x16 zv;
  #pragma unroll
  for (int i = 0; i < 16; ++i) zv[i] = 0.f;

  float m_run = -INFINITY, l_run = 0.f;
  f32x16 oacc0, oacc1;
  #pragma unroll
  for (int i = 0; i < 16; ++i) { oacc0[i] = 0.f; oacc1[i] = 0.f; }

  const __bf16* kbase = Kf + ((size_t)bh * 32 * 8) * 512 + lane * 8;
  const __bf16* vbase = Vf + ((size_t)bh * 32 * 8) * 512 + lane * 8;

#define LOADK8(K0, K1, K2, K3, K4, K5, K6, K7, jj)                            \
  do {                                                                        \
    const __bf16* _kp = kbase + (size_t)(jj) * 8 * 512;                       \
    K0 = *reinterpret_cast<const bf16x8*>(_kp);                               \
    K1 = *reinterpret_cast<const bf16x8*>(_kp + 512);                         \
    K2 = *reinterpret_cast<const bf16x8*>(_kp + 1024);                        \
    K3 = *reinterpret_cast<const bf16x8*>(_kp + 1536);                        \
    K4 = *reinterpret_cast<const bf16x8*>(_kp + 2048);                        \
    K5 = *reinterpret_cast<const bf16x8*>(_kp + 2560);                        \
    K6 = *reinterpret_cast<const bf16x8*>(_kp + 3072);                        \
    K7 = *reinterpret_cast<const bf16x8*>(_kp + 3584);                        \
    __builtin_amdgcn_sched_barrier(0);  /* pin: issue before compute */      \
  } while (0)

#define TILE64(K0, K1, K2, K3, K4, K5, K6, K7, jj)                            \
  do {                                                                        \
    /* V loads issued first and PINNED; consumed after QK + softmax */        \
    const __bf16* _vp = vbase + (size_t)(jj) * 8 * 512;                       \
    bf16x8 Va00 = *reinterpret_cast<const bf16x8*>(_vp);                      \
    bf16x8 Va01 = *reinterpret_cast<const bf16x8*>(_vp + 512);                \
    bf16x8 Vb00 = *reinterpret_cast<const bf16x8*>(_vp + 1024);               \
    bf16x8 Vb01 = *reinterpret_cast<const bf16x8*>(_vp + 1536);               \
    bf16x8 Va10 = *reinterpret_cast<const bf16x8*>(_vp + 2048);               \
    bf16x8 Va11 = *reinterpret_cast<const bf16x8*>(_vp + 2560);               \
    bf16x8 Vb10 = *reinterpret_cast<const bf16x8*>(_vp + 3072);               \
    bf16x8 Vb11 = *reinterpret_cast<const bf16x8*>(_vp + 3584);               \
    __builtin_amdgcn_sched_barrier(0);                                        \
    /* QK: two halves, two 2-deep chains each, C-in = hoisted zv */           \
    f32x16 s0a = mfma32(K0, qfr[0], zv);                                      \
    f32x16 s0b = mfma32(K1, qfr[1], zv);                                      \
    f32x16 s1a = mfma32(K4, qfr[0], zv);                                      \
    f32x16 s1b = mfma32(K5, qfr[1], zv);                                      \
    s0a = mfma32(K2, qfr[2], s0a);                                            \
    s0b = mfma32(K3, qfr[3], s0b);                                            \
    s1a = mfma32(K6, qfr[2], s1a);                                            \
    s1b = mfma32(K7, qfr[3], s1b);                                            \
    f32x16 sv0, sv1;                                                          \
    _Pragma("unroll")                                                         \
    for (int _i = 0; _i < 16; ++_i) {                                         \
      sv0[_i] = s0a[_i] + s0b[_i];                                            \
      sv1[_i] = s1a[_i] + s1b[_i];                                            \
    }                                                                         \
    if ((jj) == NT - 1) { /* diagonal tile: causal mask both halves */        \
      const int _q  = q0w + l31;                                              \
      const int _k0 = (jj) * 64 + 4 * hi;                                     \
      _Pragma("unroll")                                                       \
      for (int _r = 0; _r < 16; ++_r) {                                       \
        const int _key = _k0 + (_r & 3) + 8 * (_r >> 2);                      \
        if (_key > _q)      sv0[_r] = -INFINITY;                              \
        if (_key + 32 > _q) sv1[_r] = -INFINITY;                              \
      }                                                                       \
    }                                                                         \
    /* one max tree over 32 values */                                         \
    float _mx[16];                                                            \
    _Pragma("unroll")                                                         \
    for (int _i = 0; _i < 16; ++_i) _mx[_i] = fmaxf(sv0[_i], sv1[_i]);        \
    _Pragma("unroll")                                                         \
    for (int _s = 8; _s > 0; _s >>= 1)                                        \
      _Pragma("unroll")                                                       \
      for (int _i = 0; _i < 8; ++_i)                                          \
        if (_i < _s) _mx[_i] = fmaxf(_mx[_i], _mx[_i + _s]);                  \
    union { float f; unsigned u; } _cv; _cv.f = _mx[0];                       \
    u32x2 _sw = plswap(_cv.u, _cv.u);                                         \
    union { unsigned u; float f; } _c0, _c1; _c0.u = _sw[0]; _c1.u = _sw[1];  \
    const float _pmax = fmaxf(_c0.f, _c1.f);                                  \
    if (__any(_pmax > m_run + 8.f)) {                                         \
      const float _mn = fmaxf(m_run, _pmax);                                  \
      const float _rs = exp2f(m_run - _mn);                                   \
      l_run *= _rs;                                                           \
      _Pragma("unroll")                                                       \
      for (int _i = 0; _i < 16; ++_i) { oacc0[_i] *= _rs; oacc1[_i] *= _rs; } \
      m_run = _mn;                                                            \
    }                                                                         \
    _Pragma("unroll")                                                         \
    for (int _i = 0; _i < 16; ++_i) {                                         \
      sv0[_i] = exp2f(sv0[_i] - m_run);                                       \
      sv1[_i] = exp2f(sv1[_i] - m_run);                                       \
    }                                                                         \
    float _sm[16];                                                            \
    _Pragma("unroll")                                                         \
    for (int _i = 0; _i < 16; ++_i) _sm[_i] = sv0[_i] + sv1[_i];              \
    _Pragma("unroll")                                                         \
    for (int _s = 8; _s > 0; _s >>= 1)                                        \
      _Pragma("unroll")                                                       \
      for (int _i = 0; _i < 8; ++_i)                                          \
        if (_i < _s) _sm[_i] += _sm[_i + _s];                                 \
    l_run += _sm[0];                                                          \
    unsigned _cp0[8], _cp1[8];                                                \
    _Pragma("unroll")                                                         \
    for (int _m = 0; _m < 4; ++_m) {                                          \
      _cp0[2 * _m]     = cvtpk(sv0[4 * _m],     sv0[4 * _m + 1]);             \
      _cp0[2 * _m + 1] = cvtpk(sv0[4 * _m + 2], sv0[4 * _m + 3]);             \
      _cp1[2 * _m]     = cvtpk(sv1[4 * _m],     sv1[4 * _m + 1]);             \
      _cp1[2 * _m + 1] = cvtpk(sv1[4 * _m + 2], sv1[4 * _m + 3]);             \
    }                                                                         \
    {                                                                         \
      u32x2 _r0 = plswap(_cp0[0], _cp0[2]);                                   \
      u32x2 _r1 = plswap(_cp0[1], _cp0[3]);                                   \
      union { u32x4 u; bf16x8 v; } _pu;                                       \
      _pu.u = (u32x4){_r0[0], _r1[0], _r0[1], _r1[1]};                        \
      oacc0 = mfma32(Va00, _pu.v, oacc0);                                     \
      oacc1 = mfma32(Va10, _pu.v, oacc1);                                     \
    }                                                                         \
    {                                                                         \
      u32x2 _r0 = plswap(_cp0[4], _cp0[6]);                                   \
      u32x2 _r1 = plswap(_cp0[5], _cp0[7]);                                   \
      union { u32x4 u; bf16x8 v; } _pu;                                       \
      _pu.u = (u32x4){_r0[0], _r1[0], _r0[1], _r1[1]};                        \
      oacc0 = mfma32(Va01, _pu.v, oacc0);                                     \
      oacc1 = mfma32(Va11, _pu.v, oacc1);                                     \
    }                                                                         \
    {                                                                         \
      u32x2 _r0 = plswap(_cp1[0], _cp1[2]);                                   \
      u32x2 _r1 = plswap(_cp1[1], _cp1[3]);                                   \
      union { u32x4 u; bf16x8 v; } _pu;                                       \
      _pu.u = (u32x4){_r0[0], _r1[0], _r0[1], _r1[1]};                        \
      oacc0 = mfma32(Vb00, _pu.v, oacc0);                                     \
      oacc1 = mfma32(Vb10, _pu.v, oacc1);                                     \
    }                                                                         \
    {                                                                         \
      u32x2 _r0 = plswap(_cp1[4], _cp1[6]);                                   \
      u32x2 _r1 = plswap(_cp1[5], _cp1[7]);                                   \
      union { u32x4 u; bf16x8 v; } _pu;                                       \
      _pu.u = (u32x4){_r0[0], _r1[0], _r0[1], _r1[1]};                        \
      oacc0 = mfma32(Vb01, _pu.v, oacc0);                                     \
      oacc1 = mfma32(Vb11, _pu.v, oacc1);                                     \
    }                                                                         \
  } while (0)

  bf16x8 kA0, kA1, kA2, kA3, kA4, kA5, kA6, kA7;
  bf16x8 kB0, kB1, kB2, kB3, kB4, kB5, kB6, kB7;

  LOADK8(kA0, kA1, kA2, kA3, kA4, kA5, kA6, kA7, 0);
  int j = 0;
  #pragma unroll 1
  for (;;) {
    if (j + 1 < NT) LOADK8(kB0, kB1, kB2, kB3, kB4, kB5, kB6, kB7, j + 1);
    TILE64(kA0, kA1, kA2, kA3, kA4, kA5, kA6, kA7, j);
    if (++j >= NT) break;
    if (j + 1 < NT) LOADK8(kA0, kA1, kA2, kA3, kA4, kA5, kA6, kA7, j + 1);
    TILE64(kB0, kB1, kB2, kB3, kB4, kB5, kB6, kB7, j);
    if (++j >= NT) break;
  }
#undef TILE64
#undef LOADK8

  // ---- epilogue: O rows hd = (reg&3)+8*(reg>>2)+4hi, q col = l31 ----
  const float l_tot = l_run + __shfl_xor(l_run, 32);
  const float inv = 1.f / l_tot;
  const int b = bh >> 4, h = bh & 15;
  const int q_abs = q0w + l31;
  const size_t rowbase = ((size_t)(b * T + q_abs)) * 1024 + h * 64;
  #pragma unroll
  for (int rg = 0; rg < 4; ++rg) {
    bf16x4 o0, o1;
    #pragma unroll
    for (int r = 0; r < 4; ++r) {
      o0[r] = (__bf16)(oacc0[rg * 4 + r] * inv);
      o1[r] = (__bf16)(oacc1[rg * 4 + r] * inv);
    }
    *reinterpret_cast<bf16x4*>(&Ob[rowbase + rg * 8 + hi * 4])      = o0;
    *reinterpret_cast<bf16x4*>(&Ob[rowbase + 32 + rg * 8 + hi * 4]) = o1;
  }
}

// ---------------------------------------------------------------------------
extern "C" void kernel_launch(void* const* d_in, const int* in_sizes, int n_in,
                              void* d_out, int out_size, void* d_ws, size_t ws_size,
                              hipStream_t stream) {
  const float* x    = (const float*)d_in[0];
  const float* cosT = (const float*)d_in[1];
  const float* sinT = (const float*)d_in[2];
  // d_in[3] = mask (causal, analytic)
  const float* wq   = (const float*)d_in[4];
  const float* wk   = (const float*)d_in[5];
  const float* wv   = (const float*)d_in[6];
  const float* wo   = (const float*)d_in[7];
  float* out = (float*)d_out;

  __bf16* xb   = (__bf16*)d_ws;
  __bf16* wqb  = xb  + XSZ;
  __bf16* wkb  = wqb + WSZ;
  __bf16* wvb  = wkb + WSZ;
  __bf16* wob  = wvb + WSZ;
  __bf16* Qfb  = wob + WSZ;      // fragment-order Q (pre-scaled)
  __bf16* Kfb  = Qfb + XSZ;      // fragment-order K
  __bf16* Vfb  = Kfb + XSZ;      // fragment-order V
  __bf16* attb = Vfb + XSZ;      // [M][1024]

  cvt_all<<<(XSZ + 4 * WSZ) / 8 / 256, 256, 0, stream>>>(x, wq, wk, wv, wo, xb);

  gemm_mfma<1><<<dim3(24, 32), 256, 0, stream>>>(
      xb, wqb, wkb, wvb, cosT, sinT, Qfb, Kfb, Vfb);

  attn_v14<<<dim3(16, 32), 256, 0, stream>>>(Qfb, Kfb, Vfb, attb);

  gemm_mfma<0><<<dim3(8, 64), 256, 0, stream>>>(
      attb, wob, nullptr, nullptr, nullptr, nullptr, out, nullptr, nullptr);
}

// Round 18
// 141.275 us; speedup vs baseline: 1.4507x; 1.0159x over previous
//
#include <hip/hip_runtime.h>
#include <math.h>

constexpr int D  = 1024;
constexpr int H  = 16;
constexpr int HD = 64;
constexpr int B  = 2;
constexpr int T  = 2048;
constexpr int M  = B * T;   // 4096

constexpr size_t XSZ = (size_t)M * D;   // 4,194,304
constexpr size_t WSZ = (size_t)D * D;   // 1,048,576

typedef float  f32x4   __attribute__((ext_vector_type(4)));
typedef float  f32x16  __attribute__((ext_vector_type(16)));
typedef __bf16 bf16x8  __attribute__((ext_vector_type(8)));
typedef __bf16 bf16x4  __attribute__((ext_vector_type(4)));
typedef unsigned u32x2 __attribute__((ext_vector_type(2)));
typedef unsigned u32x4 __attribute__((ext_vector_type(4)));

static __device__ inline f32x4 mfma16(bf16x8 a, bf16x8 b, f32x4 c) {
  return __builtin_amdgcn_mfma_f32_16x16x32_bf16(a, b, c, 0, 0, 0);
}
static __device__ inline f32x16 mfma32(bf16x8 a, bf16x8 b, f32x16 c) {
  return __builtin_amdgcn_mfma_f32_32x32x16_bf16(a, b, c, 0, 0, 0);
}
// pack two f32 -> u32 of 2 bf16 (lo = a, hi = b); no builtin on gfx950
static __device__ inline unsigned cvtpk(float a, float b) {
  unsigned r;
  asm("v_cvt_pk_bf16_f32 %0, %1, %2" : "=v"(r) : "v"(a), "v"(b));
  return r;
}
static __device__ inline u32x2 plswap(unsigned a, unsigned b) {
  return __builtin_amdgcn_permlane32_swap(a, b, false, false);
}
// async global->LDS, 16B per lane (dest = wave-uniform base + lane*16)
static __device__ inline void gload16(const __bf16* g, __bf16* l) {
  __builtin_amdgcn_global_load_lds(
      (const __attribute__((address_space(1))) void*)g,
      (__attribute__((address_space(3))) void*)l, 16, 0, 0);
}

// ---------------------------------------------------------------------------
// Fused fp32->bf16 convert of x + 4 weights into contiguous bf16 workspace.
// ---------------------------------------------------------------------------
__global__ __launch_bounds__(256)
void cvt_all(const float* __restrict__ x, const float* __restrict__ wq,
             const float* __restrict__ wk, const float* __restrict__ wv,
             const float* __restrict__ wo, __bf16* __restrict__ out) {
  size_t idx = ((size_t)blockIdx.x * 256 + threadIdx.x) * 8;
  const float* src;
  if      (idx < XSZ)            src = x  + idx;
  else if (idx < XSZ + WSZ)      src = wq + (idx - XSZ);
  else if (idx < XSZ + 2 * WSZ)  src = wk + (idx - XSZ - WSZ);
  else if (idx < XSZ + 3 * WSZ)  src = wv + (idx - XSZ - 2 * WSZ);
  else                           src = wo + (idx - XSZ - 3 * WSZ);
  float4 a = *reinterpret_cast<const float4*>(src);
  float4 b = *reinterpret_cast<const float4*>(src + 4);
  bf16x8 o;
  o[0] = (__bf16)a.x; o[1] = (__bf16)a.y; o[2] = (__bf16)a.z; o[3] = (__bf16)a.w;
  o[4] = (__bf16)b.x; o[5] = (__bf16)b.y; o[6] = (__bf16)b.z; o[7] = (__bf16)b.w;
  *reinterpret_cast<bf16x8*>(out + idx) = o;
}

// ---------------------------------------------------------------------------
// MFMA GEMM. MODE 1: 128x128 tile, fused QKV -> fragment-order Q/K/V.
// MODE 0: 64x128 tile (grid (8,64)=512 blocks = 2/CU), fp32 out.
// Both: BK=64, 256 thr = 4 waves (2x2), global_load_lds staging.
// ---------------------------------------------------------------------------
template<int MODE>
__global__ __launch_bounds__(256)
void gemm_mfma(const __bf16* __restrict__ A,
               const __bf16* __restrict__ W0, const __bf16* __restrict__ W1,
               const __bf16* __restrict__ W2,
               const float* __restrict__ cosT, const float* __restrict__ sinT,
               void* __restrict__ out0, void* __restrict__ out1,
               void* __restrict__ out2) {
  constexpr int BM  = (MODE == 0) ? 64 : 128;   // rows per block
  constexpr int NMT = BM / 32;                  // per-wave m-frags (2 or 4)
  __shared__ __bf16 As[BM * 64];
  __shared__ __bf16 Bs[128 * 64];

  const int tid  = threadIdx.x;
  const int lane = tid & 63;
  const int w    = tid >> 6;     // 0..3
  const int wm   = w >> 1;       // 0..1
  const int wn   = w & 1;        // 0..1 (64 cols each)
  const int l15  = lane & 15, lg = lane >> 4;
  const int m0   = blockIdx.y * BM;

  int which, n0;
  const __bf16* Bw;
  if (MODE == 1) {
    which = blockIdx.x >> 3;
    n0 = (blockIdx.x & 7) * 128;
    Bw = which == 0 ? W0 : which == 1 ? W1 : W2;
  } else {
    which = 0;
    n0 = blockIdx.x * 128;
    Bw = W0;
  }

  f32x4 acc[NMT][4];
  #pragma unroll
  for (int i = 0; i < NMT; ++i)
    #pragma unroll
    for (int j = 0; j < 4; ++j) acc[i][j] = (f32x4){0.f, 0.f, 0.f, 0.f};

  const int r0 = tid >> 3;          // 0..31
  const int c0 = (tid & 7) * 8;     // 0..56

  for (int k0 = 0; k0 < 1024; k0 += 64) {
    #pragma unroll
    for (int i = 0; i < BM / 32; ++i)
      gload16(A + (size_t)(m0 + r0 + 32 * i) * 1024 + k0 + c0,
              As + (tid + 256 * i) * 8);
    #pragma unroll
    for (int i = 0; i < 4; ++i)
      gload16(Bw + (size_t)(n0 + r0 + 32 * i) * 1024 + k0 + c0,
              Bs + (tid + 256 * i) * 8);
    __syncthreads();   // drains vmcnt -> LDS tiles ready

    #pragma unroll
    for (int ks = 0; ks < 2; ++ks) {
      bf16x8 af[NMT], bfr[4];
      #pragma unroll
      for (int mt = 0; mt < NMT; ++mt)
        af[mt] = *reinterpret_cast<const bf16x8*>(
            &As[(wm * (BM / 2) + mt * 16 + l15) * 64 + ks * 32 + lg * 8]);
      #pragma unroll
      for (int nt = 0; nt < 4; ++nt)
        bfr[nt] = *reinterpret_cast<const bf16x8*>(
            &Bs[(wn * 64 + nt * 16 + l15) * 64 + ks * 32 + lg * 8]);
      #pragma unroll
      for (int mt = 0; mt < NMT; ++mt)
        #pragma unroll
        for (int nt = 0; nt < 4; ++nt)
          acc[mt][nt] = mfma16(af[mt], bfr[nt], acc[mt][nt]);
    }
    __syncthreads();
  }

  // Frag: n = n0 + wn*64 + nt*16 + l15 ; m = m0 + wm*(BM/2) + mt*16 + lg*4 + r
  if (MODE == 0) {
    float* o = (float*)out0;
    #pragma unroll
    for (int mt = 0; mt < NMT; ++mt) {
      const int mb = m0 + wm * (BM / 2) + mt * 16 + lg * 4;
      #pragma unroll
      for (int nt = 0; nt < 4; ++nt) {
        const int n = n0 + wn * 64 + nt * 16 + l15;
        #pragma unroll
        for (int r = 0; r < 4; ++r)
          o[(size_t)(mb + r) * 1024 + n] = acc[mt][nt][r];
      }
    }
  } else if (which < 2) {
    // Q or K: RoPE fused; Q scaled by 0.125*log2(e). Fragment-order store:
    //   Q: [bh][t>>5][st][L][e]   K: [bh][t>>6][(t>>5)&1][st][L][e]
    __bf16* dst = which == 0 ? (__bf16*)out0 : (__bf16*)out1;
    const float qs = (which == 0) ? 0.180336880f : 1.0f;
    const int h = (n0 + wn * 64) >> 6;
    const int e  = l15 & 7;
    const int Lh = (l15 >> 3) << 5;
    #pragma unroll
    for (int mt = 0; mt < NMT; ++mt) {
      const int tb   = m0 + wm * (BM / 2) + mt * 16 + lg * 4;
      const int bb   = tb >> 11;
      const int tloc = tb & 2047;
      const int bh   = bb * H + h;
      #pragma unroll
      for (int r = 0; r < 4; ++r) {
        const int t = tloc + r;
        const int L = (t & 31) + Lh;
        size_t fb;
        if (which == 0)
          fb = ((size_t)bh * 64 + (t >> 5)) * 4;
        else
          fb = (((size_t)bh * 32 + (t >> 6)) * 2 + ((t >> 5) & 1)) * 4;
        #pragma unroll
        for (int nt = 0; nt < 2; ++nt) {
          const int hd = nt * 16 + l15;
          const float c = cosT[t * HD + hd];
          const float s = sinT[t * HD + hd];
          const float v1 = acc[mt][nt][r];
          const float v2 = acc[mt][nt + 2][r];
          dst[(fb + nt)     * 512 + L * 8 + e] = (__bf16)((v1 * c - v2 * s) * qs);
          dst[(fb + nt + 2) * 512 + L * 8 + e] = (__bf16)((v2 * c + v1 * s) * qs);
        }
      }
    }
  } else {
    // V: PV-fragment order [bh][t>>6][dg=hd>>5][kc=(t&63)>>4][L][e]
    __bf16* dst = (__bf16*)out2;
    const int h = (n0 + wn * 64) >> 6;
    #pragma unroll
    for (int mt = 0; mt < NMT; ++mt) {
      const int tb   = m0 + wm * (BM / 2) + mt * 16 + lg * 4;
      const int bb   = tb >> 11;
      const int tloc = tb & 2047;
      const int bh   = bb * H + h;
      const int jt   = tloc >> 6;
      const int kt   = tloc & 63;
      const int Lk   = ((kt >> 3) & 1) << 5;
      const int e0   = kt & 7;
      const size_t fb = (((size_t)bh * 32 + jt) * 2) * 4 + (kt >> 4);
      #pragma unroll
      for (int nt = 0; nt < 4; ++nt) {
        const int hd = nt * 16 + l15;
        const int dg = hd >> 5;
        const int L  = (hd & 31) + Lk;
        bf16x4 ov;
        #pragma unroll
        for (int r = 0; r < 4; ++r) ov[r] = (__bf16)acc[mt][nt][r];
        *reinterpret_cast<bf16x4*>(
            &dst[(fb + (size_t)dg * 4) * 512 + L * 8 + e0]) = ov;
      }
    }
  }
}

// ---------------------------------------------------------------------------
// attn_v15: v13 + 2-tile software pipeline (T15-style):
// per iteration: QK(j+1) MFMAs issue FIRST, then softmax(j) runs on the VALU
// while those MFMAs drain (separate pipes), then PV(j). Breaks the per-tile
// QK->softmax serial dependency that held issue util at ~45%.
// Two named sv states (svA/svB, 2-phase unrolled loop — no runtime index).
// QK = two 4-deep MFMA chains (latency hidden by a full softmax+PV; the
// 32 VALU adds of the old 2-chain+add form are deleted).
// K double-buffered; V issued at iteration top, used ~400cy later.
// ---------------------------------------------------------------------------
__global__ __launch_bounds__(256, 2)
void attn_v15(const __bf16* __restrict__ Qf, const __bf16* __restrict__ Kf,
              const __bf16* __restrict__ Vf, __bf16* __restrict__ Ob) {
  const int tid  = threadIdx.x;
  const int lane = tid & 63;
  const int w    = tid >> 6;          // 0..3
  const int l31  = lane & 31;
  const int hi   = lane >> 5;         // 0..1
  const int bx   = blockIdx.x;        // 0..15
  const int by   = blockIdx.y;        // 0..31
  const int bh   = (bx & 7) + 8 * (by >> 3);   // XCD = bh&7
  const int x    = (bx >> 3) + 2 * (by & 7);   // 0..15

  const int wi = (bh < 16) ? w : (w ^ 1);
  const int qt = (wi == 0) ? 2 * x : (wi == 1) ? 63 - 2 * x
               : (wi == 2) ? 2 * x + 1 : 62 - 2 * x;
  const int q0w = qt * 32;
  const int NT  = (qt >> 1) + 1;      // 64-key tiles

  // Q fragments: 4 coalesced loads
  const __bf16* qbase = Qf + (((size_t)bh * 64 + qt) * 4) * 512 + lane * 8;
  bf16x8 qfr[4];
  #pragma unroll
  for (int st = 0; st < 4; ++st)
    qfr[st] = *reinterpret_cast<const bf16x8*>(qbase + st * 512);

  f32x16 zv;
  #pragma unroll
  for (int i = 0; i < 16; ++i) zv[i] = 0.f;

  float m_run = -INFINITY, l_run = 0.f;
  f32x16 oacc0, oacc1;
  #pragma unroll
  for (int i = 0; i < 16; ++i) { oacc0[i] = 0.f; oacc1[i] = 0.f; }

  const __bf16* kbase = Kf + ((size_t)bh * 32 * 8) * 512 + lane * 8;
  const __bf16* vbase = Vf + ((size_t)bh * 32 * 8) * 512 + lane * 8;

#define LOADK8(K0, K1, K2, K3, K4, K5, K6, K7, jj)                            \
  do {                                                                        \
    const __bf16* _kp = kbase + (size_t)(jj) * 8 * 512;                       \
    K0 = *reinterpret_cast<const bf16x8*>(_kp);                               \
    K1 = *reinterpret_cast<const bf16x8*>(_kp + 512);                         \
    K2 = *reinterpret_cast<const bf16x8*>(_kp + 1024);                        \
    K3 = *reinterpret_cast<const bf16x8*>(_kp + 1536);                        \
    K4 = *reinterpret_cast<const bf16x8*>(_kp + 2048);                        \
    K5 = *reinterpret_cast<const bf16x8*>(_kp + 2560);                        \
    K6 = *reinterpret_cast<const bf16x8*>(_kp + 3072);                        \
    K7 = *reinterpret_cast<const bf16x8*>(_kp + 3584);                        \
    __builtin_amdgcn_sched_barrier(0);                                        \
  } while (0)

#define LOADV8(jj)                                                            \
  do {                                                                        \
    const __bf16* _vp = vbase + (size_t)(jj) * 8 * 512;                       \
    VV0 = *reinterpret_cast<const bf16x8*>(_vp);                              \
    VV1 = *reinterpret_cast<const bf16x8*>(_vp + 512);                        \
    VV2 = *reinterpret_cast<const bf16x8*>(_vp + 1024);                       \
    VV3 = *reinterpret_cast<const bf16x8*>(_vp + 1536);                       \
    VV4 = *reinterpret_cast<const bf16x8*>(_vp + 2048);                       \
    VV5 = *reinterpret_cast<const bf16x8*>(_vp + 2560);                       \
    VV6 = *reinterpret_cast<const bf16x8*>(_vp + 3072);                       \
    VV7 = *reinterpret_cast<const bf16x8*>(_vp + 3584);                       \
    __builtin_amdgcn_sched_barrier(0);                                        \
  } while (0)

// QK: two 4-deep MFMA chains; results land in SV0/SV1 (consumed NEXT phase)
#define QK64(SV0, SV1, K0, K1, K2, K3, K4, K5, K6, K7)                        \
  do {                                                                        \
    SV0 = mfma32(K0, qfr[0], zv);                                             \
    SV0 = mfma32(K1, qfr[1], SV0);                                            \
    SV0 = mfma32(K2, qfr[2], SV0);                                            \
    SV0 = mfma32(K3, qfr[3], SV0);                                            \
    SV1 = mfma32(K4, qfr[0], zv);                                             \
    SV1 = mfma32(K5, qfr[1], SV1);                                            \
    SV1 = mfma32(K6, qfr[2], SV1);                                            \
    SV1 = mfma32(K7, qfr[3], SV1);                                            \
  } while (0)

#define SMPV(SV0, SV1, jj)                                                    \
  do {                                                                        \
    if ((jj) == NT - 1) { /* diagonal tile: causal mask both halves */        \
      const int _q  = q0w + l31;                                              \
      const int _k0 = (jj) * 64 + 4 * hi;                                     \
      _Pragma("unroll")                                                       \
      for (int _r = 0; _r < 16; ++_r) {                                       \
        const int _key = _k0 + (_r & 3) + 8 * (_r >> 2);                      \
        if (_key > _q)      SV0[_r] = -INFINITY;                              \
        if (_key + 32 > _q) SV1[_r] = -INFINITY;                              \
      }                                                                       \
    }                                                                         \
    float _mx[16];                                                            \
    _Pragma("unroll")                                                         \
    for (int _i = 0; _i < 16; ++_i) _mx[_i] = fmaxf(SV0[_i], SV1[_i]);        \
    _Pragma("unroll")                                                         \
    for (int _s = 8; _s > 0; _s >>= 1)                                        \
      _Pragma("unroll")                                                       \
      for (int _i = 0; _i < 8; ++_i)                                          \
        if (_i < _s) _mx[_i] = fmaxf(_mx[_i], _mx[_i + _s]);                  \
    union { float f; unsigned u; } _cv; _cv.f = _mx[0];                       \
    u32x2 _sw = plswap(_cv.u, _cv.u);                                         \
    union { unsigned u; float f; } _c0, _c1; _c0.u = _sw[0]; _c1.u = _sw[1];  \
    const float _pmax = fmaxf(_c0.f, _c1.f);                                  \
    if (__any(_pmax > m_run + 8.f)) {                                         \
      const float _mn = fmaxf(m_run, _pmax);                                  \
      const float _rs = exp2f(m_run - _mn);                                   \
      l_run *= _rs;                                                           \
      _Pragma("unroll")                                                       \
      for (int _i = 0; _i < 16; ++_i) { oacc0[_i] *= _rs; oacc1[_i] *= _rs; } \
      m_run = _mn;                                                            \
    }                                                                         \
    _Pragma("unroll")                                                         \
    for (int _i = 0; _i < 16; ++_i) {                                         \
      SV0[_i] = exp2f(SV0[_i] - m_run);                                       \
      SV1[_i] = exp2f(SV1[_i] - m_run);                                       \
    }                                                                         \
    float _sm[16];                                                            \
    _Pragma("unroll")                                                         \
    for (int _i = 0; _i < 16; ++_i) _sm[_i] = SV0[_i] + SV1[_i];              \
    _Pragma("unroll")                                                         \
    for (int _s = 8; _s > 0; _s >>= 1)                                        \
      _Pragma("unroll")                                                       \
      for (int _i = 0; _i < 8; ++_i)                                          \
        if (_i < _s) _sm[_i] += _sm[_i + _s];                                 \
    l_run += _sm[0];                                                          \
    unsigned _cp0[8], _cp1[8];                                                \
    _Pragma("unroll")                                                         \
    for (int _m = 0; _m < 4; ++_m) {                                          \
      _cp0[2 * _m]     = cvtpk(SV0[4 * _m],     SV0[4 * _m + 1]);             \
      _cp0[2 * _m + 1] = cvtpk(SV0[4 * _m + 2], SV0[4 * _m + 3]);             \
      _cp1[2 * _m]     = cvtpk(SV1[4 * _m],     SV1[4 * _m + 1]);             \
      _cp1[2 * _m + 1] = cvtpk(SV1[4 * _m + 2], SV1[4 * _m + 3]);             \
    }                                                                         \
    {                                                                         \
      u32x2 _r0 = plswap(_cp0[0], _cp0[2]);                                   \
      u32x2 _r1 = plswap(_cp0[1], _cp0[3]);                                   \
      union { u32x4 u; bf16x8 v; } _pu;                                       \
      _pu.u = (u32x4){_r0[0], _r1[0], _r0[1], _r1[1]};                        \
      oacc0 = mfma32(VV0, _pu.v, oacc0);                                      \
      oacc1 = mfma32(VV4, _pu.v, oacc1);                                      \
    }                                                                         \
    {                                                                         \
      u32x2 _r0 = plswap(_cp0[4], _cp0[6]);                                   \
      u32x2 _r1 = plswap(_cp0[5], _cp0[7]);                                   \
      union { u32x4 u; bf16x8 v; } _pu;                                       \
      _pu.u = (u32x4){_r0[0], _r1[0], _r0[1], _r1[1]};                        \
      oacc0 = mfma32(VV1, _pu.v, oacc0);                                      \
      oacc1 = mfma32(VV5, _pu.v, oacc1);                                      \
    }                                                                         \
    {                                                                         \
      u32x2 _r0 = plswap(_cp1[0], _cp1[2]);                                   \
      u32x2 _r1 = plswap(_cp1[1], _cp1[3]);                                   \
      union { u32x4 u; bf16x8 v; } _pu;                                       \
      _pu.u = (u32x4){_r0[0], _r1[0], _r0[1], _r1[1]};                        \
      oacc0 = mfma32(VV2, _pu.v, oacc0);                                      \
      oacc1 = mfma32(VV6, _pu.v, oacc1);                                      \
    }                                                                         \
    {                                                                         \
      u32x2 _r0 = plswap(_cp1[4], _cp1[6]);                                   \
      u32x2 _r1 = plswap(_cp1[5], _cp1[7]);                                   \
      union { u32x4 u; bf16x8 v; } _pu;                                       \
      _pu.u = (u32x4){_r0[0], _r1[0], _r0[1], _r1[1]};                        \
      oacc0 = mfma32(VV3, _pu.v, oacc0);                                      \
      oacc1 = mfma32(VV7, _pu.v, oacc1);                                      \
    }                                                                         \
  } while (0)

  bf16x8 kA0, kA1, kA2, kA3, kA4, kA5, kA6, kA7;
  bf16x8 kB0, kB1, kB2, kB3, kB4, kB5, kB6, kB7;
  bf16x8 VV0, VV1, VV2, VV3, VV4, VV5, VV6, VV7;
  f32x16 svA0, svA1, svB0, svB1;

  // Prologue: K(0) -> QK(0) into svA; K(1) into kB.
  LOADK8(kA0, kA1, kA2, kA3, kA4, kA5, kA6, kA7, 0);
  QK64(svA0, svA1, kA0, kA1, kA2, kA3, kA4, kA5, kA6, kA7);
  if (1 < NT) LOADK8(kB0, kB1, kB2, kB3, kB4, kB5, kB6, kB7, 1);

  int j = 0;
  #pragma unroll 1
  for (;;) {
    // phase A: tile j in svA; K(j+1) in kB; K(j+2) -> kA
    LOADV8(j);
    if (j + 1 < NT)
      QK64(svB0, svB1, kB0, kB1, kB2, kB3, kB4, kB5, kB6, kB7);
    if (j + 2 < NT)
      LOADK8(kA0, kA1, kA2, kA3, kA4, kA5, kA6, kA7, j + 2);
    SMPV(svA0, svA1, j);
    if (++j >= NT) break;

    // phase B: tile j in svB; K(j+1) in kA; K(j+2) -> kB
    LOADV8(j);
    if (j + 1 < NT)
      QK64(svA0, svA1, kA0, kA1, kA2, kA3, kA4, kA5, kA6, kA7);
    if (j + 2 < NT)
      LOADK8(kB0, kB1, kB2, kB3, kB4, kB5, kB6, kB7, j + 2);
    SMPV(svB0, svB1, j);
    if (++j >= NT) break;
  }
#undef SMPV
#undef QK64
#undef LOADV8
#undef LOADK8

  // ---- epilogue: O rows hd = (reg&3)+8*(reg>>2)+4hi, q col = l31 ----
  const float l_tot = l_run + __shfl_xor(l_run, 32);
  const float inv = 1.f / l_tot;
  const int b = bh >> 4, h = bh & 15;
  const int q_abs = q0w + l31;
  const size_t rowbase = ((size_t)(b * T + q_abs)) * 1024 + h * 64;
  #pragma unroll
  for (int rg = 0; rg < 4; ++rg) {
    bf16x4 o0, o1;
    #pragma unroll
    for (int r = 0; r < 4; ++r) {
      o0[r] = (__bf16)(oacc0[rg * 4 + r] * inv);
      o1[r] = (__bf16)(oacc1[rg * 4 + r] * inv);
    }
    *reinterpret_cast<bf16x4*>(&Ob[rowbase + rg * 8 + hi * 4])      = o0;
    *reinterpret_cast<bf16x4*>(&Ob[rowbase + 32 + rg * 8 + hi * 4]) = o1;
  }
}

// ---------------------------------------------------------------------------
extern "C" void kernel_launch(void* const* d_in, const int* in_sizes, int n_in,
                              void* d_out, int out_size, void* d_ws, size_t ws_size,
                              hipStream_t stream) {
  const float* x    = (const float*)d_in[0];
  const float* cosT = (const float*)d_in[1];
  const float* sinT = (const float*)d_in[2];
  // d_in[3] = mask (causal, analytic)
  const float* wq   = (const float*)d_in[4];
  const float* wk   = (const float*)d_in[5];
  const float* wv   = (const float*)d_in[6];
  const float* wo   = (const float*)d_in[7];
  float* out = (float*)d_out;

  __bf16* xb   = (__bf16*)d_ws;
  __bf16* wqb  = xb  + XSZ;
  __bf16* wkb  = wqb + WSZ;
  __bf16* wvb  = wkb + WSZ;
  __bf16* wob  = wvb + WSZ;
  __bf16* Qfb  = wob + WSZ;      // fragment-order Q (pre-scaled)
  __bf16* Kfb  = Qfb + XSZ;      // fragment-order K
  __bf16* Vfb  = Kfb + XSZ;      // fragment-order V
  __bf16* attb = Vfb + XSZ;      // [M][1024]

  cvt_all<<<(XSZ + 4 * WSZ) / 8 / 256, 256, 0, stream>>>(x, wq, wk, wv, wo, xb);

  gemm_mfma<1><<<dim3(24, 32), 256, 0, stream>>>(
      xb, wqb, wkb, wvb, cosT, sinT, Qfb, Kfb, Vfb);

  attn_v15<<<dim3(16, 32), 256, 0, stream>>>(Qfb, Kfb, Vfb, attb);

  gemm_mfma<0><<<dim3(8, 64), 256, 0, stream>>>(
      attb, wob, nullptr, nullptr, nullptr, nullptr, out, nullptr, nullptr);
}